// Round 10
// baseline (1310.105 us; speedup 1.0000x reference)
//
#include <hip/hip_runtime.h>
#include <hip/hip_fp16.h>
#include <stdint.h>

#define HDIM 2048
#define BATCH 16
#define TLEN 512
#define TH   1048576        // TLEN*HDIM
#define OUT_MAIN 16777216   // BATCH*TLEN*HDIM

using floatx4 = __attribute__((ext_vector_type(4))) float;
using shortx8 = __attribute__((ext_vector_type(8))) short;
using halfx8  = __attribute__((ext_vector_type(8))) _Float16;
typedef unsigned long long ull;

static __device__ __forceinline__ unsigned f16bits(float f) {
    _Float16 h = (_Float16)f;
    return (unsigned)*(unsigned short*)&h;
}

// ---------------- cast kernels ----------------
__global__ void cast_x_kernel(const float* __restrict__ x, _Float16* __restrict__ xh, int n) {
    int i = blockIdx.x * blockDim.x + threadIdx.x;
    int stride = gridDim.x * blockDim.x;
    for (; i < n; i += stride) xh[i] = (_Float16)x[i];
}

__global__ void cast_w_kernel(const float* __restrict__ W,
                              _Float16* __restrict__ wxh,
                              _Float16* __restrict__ whh) {
    int i = blockIdx.x * blockDim.x + threadIdx.x;
    int stride = gridDim.x * blockDim.x;
    for (; i < HDIM * HDIM; i += stride) {
        int g = i >> 11, k = i & (HDIM - 1);
        wxh[i] = (_Float16)W[g * (2 * HDIM) + k];
        whh[i] = (_Float16)W[g * (2 * HDIM) + HDIM + k];
    }
}

// Transpose Wh -> whT (fp16). Runs after gemm_u; output aliases dead xh.
__global__ void transpose_wh_kernel(const float* __restrict__ W,
                                    _Float16* __restrict__ whT) {
    __shared__ float tile[32][33];
    int bx = blockIdx.x * 32, by = blockIdx.y * 32;
    int tx = threadIdx.x, ty = threadIdx.y;  // (32,8)
#pragma unroll
    for (int r = 0; r < 32; r += 8)
        tile[ty + r][tx] = W[(size_t)(by + ty + r) * (2 * HDIM) + HDIM + bx + tx];
    __syncthreads();
#pragma unroll
    for (int r = 0; r < 32; r += 8)
        whT[(size_t)(bx + ty + r) * HDIM + by + tx] = (_Float16)tile[tx][ty + r];
}

// ---------------- phase A: u = x @ Wx^T + b -> out (fp32) + uh (fp16) ----------------
__global__ __launch_bounds__(256) void gemm_u_kernel(
    const _Float16* __restrict__ xh,
    const _Float16* __restrict__ wxh,
    const float* __restrict__ bias,
    float* __restrict__ out,
    _Float16* __restrict__ uh)
{
    __shared__ __align__(16) short As[4 * 128 * 8];
    __shared__ __align__(16) short Bs[4 * 128 * 8];

    const int j = threadIdx.x;
    const int m0 = blockIdx.x * 128;
    const int n0 = blockIdx.y * 128;
    const int w = j >> 6, lane = j & 63;
    const int wm = (w >> 1) * 64, wn = (w & 1) * 64;
    const int quad = lane >> 4, l15 = lane & 15;

    const int mA0 = j & 127, kg0 = j >> 7;
    const int mA1 = (j + 256) & 127, kg1 = (j + 256) >> 7;

    floatx4 acc[4][4] = {};

    shortx8 ra0 = *(const shortx8*)(xh  + (size_t)(m0 + mA0) * HDIM + kg0 * 8);
    shortx8 ra1 = *(const shortx8*)(xh  + (size_t)(m0 + mA1) * HDIM + kg1 * 8);
    shortx8 rb0 = *(const shortx8*)(wxh + (size_t)(n0 + mA0) * HDIM + kg0 * 8);
    shortx8 rb1 = *(const shortx8*)(wxh + (size_t)(n0 + mA1) * HDIM + kg1 * 8);

    for (int kt = 0; kt < 64; ++kt) {
        ((shortx8*)As)[kg0 * 128 + mA0] = ra0;
        ((shortx8*)As)[kg1 * 128 + mA1] = ra1;
        ((shortx8*)Bs)[kg0 * 128 + mA0] = rb0;
        ((shortx8*)Bs)[kg1 * 128 + mA1] = rb1;
        __syncthreads();

        if (kt < 63) {
            int k = (kt + 1) * 32;
            ra0 = *(const shortx8*)(xh  + (size_t)(m0 + mA0) * HDIM + k + kg0 * 8);
            ra1 = *(const shortx8*)(xh  + (size_t)(m0 + mA1) * HDIM + k + kg1 * 8);
            rb0 = *(const shortx8*)(wxh + (size_t)(n0 + mA0) * HDIM + k + kg0 * 8);
            rb1 = *(const shortx8*)(wxh + (size_t)(n0 + mA1) * HDIM + k + kg1 * 8);
        }

        halfx8 af[4], bf[4];
#pragma unroll
        for (int mt = 0; mt < 4; ++mt)
            af[mt] = ((const halfx8*)As)[quad * 128 + wm + mt * 16 + l15];
#pragma unroll
        for (int nt = 0; nt < 4; ++nt)
            bf[nt] = ((const halfx8*)Bs)[quad * 128 + wn + nt * 16 + l15];
#pragma unroll
        for (int mt = 0; mt < 4; ++mt)
#pragma unroll
            for (int nt = 0; nt < 4; ++nt)
                acc[mt][nt] = __builtin_amdgcn_mfma_f32_16x16x32_f16(af[mt], bf[nt], acc[mt][nt], 0, 0, 0);
        __syncthreads();
    }

#pragma unroll
    for (int nt = 0; nt < 4; ++nt) {
        int gn = n0 + wn + nt * 16 + l15;
        float bv = bias[gn];
#pragma unroll
        for (int mt = 0; mt < 4; ++mt) {
#pragma unroll
            for (int r = 0; r < 4; ++r) {
                int gm = m0 + wm + mt * 16 + quad * 4 + r;
                float v = acc[mt][nt][r] + bv;
                out[(size_t)gm * HDIM + gn] = v;
                uh[(size_t)gm * HDIM + gn] = (_Float16)v;
            }
        }
    }
}

// ---------------- Wh2 = Wh*Wh (fp16 single-plane) ----------------
__global__ __launch_bounds__(256) void gemm_w2_kernel(
    const _Float16* __restrict__ whh,
    const _Float16* __restrict__ wT,
    _Float16* __restrict__ w2)
{
    __shared__ __align__(16) short As[4 * 128 * 8];
    __shared__ __align__(16) short Bs[4 * 128 * 8];

    const int j = threadIdx.x;
    const int m0 = blockIdx.x * 128;
    const int n0 = blockIdx.y * 128;
    const int w = j >> 6, lane = j & 63;
    const int wm = (w >> 1) * 64, wn = (w & 1) * 64;
    const int quad = lane >> 4, l15 = lane & 15;

    const int mA0 = j & 127, kg0 = j >> 7;
    const int mA1 = (j + 256) & 127, kg1 = (j + 256) >> 7;

    floatx4 acc[4][4] = {};

    shortx8 ra0 = *(const shortx8*)(whh + (size_t)(m0 + mA0) * HDIM + kg0 * 8);
    shortx8 ra1 = *(const shortx8*)(whh + (size_t)(m0 + mA1) * HDIM + kg1 * 8);
    shortx8 rb0 = *(const shortx8*)(wT  + (size_t)(n0 + mA0) * HDIM + kg0 * 8);
    shortx8 rb1 = *(const shortx8*)(wT  + (size_t)(n0 + mA1) * HDIM + kg1 * 8);

    for (int kt = 0; kt < 64; ++kt) {
        ((shortx8*)As)[kg0 * 128 + mA0] = ra0;
        ((shortx8*)As)[kg1 * 128 + mA1] = ra1;
        ((shortx8*)Bs)[kg0 * 128 + mA0] = rb0;
        ((shortx8*)Bs)[kg1 * 128 + mA1] = rb1;
        __syncthreads();

        if (kt < 63) {
            int k = (kt + 1) * 32;
            ra0 = *(const shortx8*)(whh + (size_t)(m0 + mA0) * HDIM + k + kg0 * 8);
            ra1 = *(const shortx8*)(whh + (size_t)(m0 + mA1) * HDIM + k + kg1 * 8);
            rb0 = *(const shortx8*)(wT  + (size_t)(n0 + mA0) * HDIM + k + kg0 * 8);
            rb1 = *(const shortx8*)(wT  + (size_t)(n0 + mA1) * HDIM + k + kg1 * 8);
        }

        halfx8 af[4], bf[4];
#pragma unroll
        for (int mt = 0; mt < 4; ++mt)
            af[mt] = ((const halfx8*)As)[quad * 128 + wm + mt * 16 + l15];
#pragma unroll
        for (int nt = 0; nt < 4; ++nt)
            bf[nt] = ((const halfx8*)Bs)[quad * 128 + wn + nt * 16 + l15];
#pragma unroll
        for (int mt = 0; mt < 4; ++mt)
#pragma unroll
            for (int nt = 0; nt < 4; ++nt)
                acc[mt][nt] = __builtin_amdgcn_mfma_f32_16x16x32_f16(af[mt], bf[nt], acc[mt][nt], 0, 0, 0);
        __syncthreads();
    }

#pragma unroll
    for (int nt = 0; nt < 4; ++nt) {
        int gn = n0 + wn + nt * 16 + l15;
#pragma unroll
        for (int mt = 0; mt < 4; ++mt)
#pragma unroll
            for (int r = 0; r < 4; ++r) {
                int gm = m0 + wm + mt * 16 + quad * 4 + r;
                w2[(size_t)gm * HDIM + gn] = (_Float16)acc[mt][nt][r];
            }
    }
}

// ---------------- v = u + Wh*u_shift (fp16; t==0 rows keep u) ----------------
__global__ __launch_bounds__(256) void gemm_v_kernel(
    const _Float16* __restrict__ uh,
    const _Float16* __restrict__ whh,
    float* __restrict__ out)
{
    __shared__ __align__(16) short As[4 * 128 * 8];
    __shared__ __align__(16) short Bs[4 * 128 * 8];

    const int j = threadIdx.x;
    const int m0 = blockIdx.x * 128;
    const int n0 = blockIdx.y * 128;
    const int w = j >> 6, lane = j & 63;
    const int wm = (w >> 1) * 64, wn = (w & 1) * 64;
    const int quad = lane >> 4, l15 = lane & 15;

    const int mA0 = j & 127, kg0 = j >> 7;
    const int mA1 = (j + 256) & 127, kg1 = (j + 256) >> 7;

    int rowA0 = m0 + mA0 - 1; if (rowA0 < 0) rowA0 = 0;
    int rowA1 = m0 + mA1 - 1; if (rowA1 < 0) rowA1 = 0;

    floatx4 acc[4][4] = {};

    shortx8 ra0 = *(const shortx8*)(uh  + (size_t)rowA0 * HDIM + kg0 * 8);
    shortx8 ra1 = *(const shortx8*)(uh  + (size_t)rowA1 * HDIM + kg1 * 8);
    shortx8 rb0 = *(const shortx8*)(whh + (size_t)(n0 + mA0) * HDIM + kg0 * 8);
    shortx8 rb1 = *(const shortx8*)(whh + (size_t)(n0 + mA1) * HDIM + kg1 * 8);

    for (int kt = 0; kt < 64; ++kt) {
        ((shortx8*)As)[kg0 * 128 + mA0] = ra0;
        ((shortx8*)As)[kg1 * 128 + mA1] = ra1;
        ((shortx8*)Bs)[kg0 * 128 + mA0] = rb0;
        ((shortx8*)Bs)[kg1 * 128 + mA1] = rb1;
        __syncthreads();

        if (kt < 63) {
            int k = (kt + 1) * 32;
            ra0 = *(const shortx8*)(uh  + (size_t)rowA0 * HDIM + k + kg0 * 8);
            ra1 = *(const shortx8*)(uh  + (size_t)rowA1 * HDIM + k + kg1 * 8);
            rb0 = *(const shortx8*)(whh + (size_t)(n0 + mA0) * HDIM + k + kg0 * 8);
            rb1 = *(const shortx8*)(whh + (size_t)(n0 + mA1) * HDIM + k + kg1 * 8);
        }

        halfx8 af[4], bf[4];
#pragma unroll
        for (int mt = 0; mt < 4; ++mt)
            af[mt] = ((const halfx8*)As)[quad * 128 + wm + mt * 16 + l15];
#pragma unroll
        for (int nt = 0; nt < 4; ++nt)
            bf[nt] = ((const halfx8*)Bs)[quad * 128 + wn + nt * 16 + l15];
#pragma unroll
        for (int mt = 0; mt < 4; ++mt)
#pragma unroll
            for (int nt = 0; nt < 4; ++nt)
                acc[mt][nt] = __builtin_amdgcn_mfma_f32_16x16x32_f16(af[mt], bf[nt], acc[mt][nt], 0, 0, 0);
        __syncthreads();
    }

#pragma unroll
    for (int nt = 0; nt < 4; ++nt) {
        int gn = n0 + wn + nt * 16 + l15;
#pragma unroll
        for (int mt = 0; mt < 4; ++mt)
#pragma unroll
            for (int r = 0; r < 4; ++r) {
                int gm = m0 + wm + mt * 16 + quad * 4 + r;
                float uval = out[(size_t)gm * HDIM + gn];
                float res = ((gm & 511) == 0) ? uval : (acc[mt][nt][r] + uval);
                out[(size_t)gm * HDIM + gn] = res;
            }
    }
}

// ---------------- phase B: two parity chains, fp16 ring, WAVE-LOCAL publish ----------------
// o_t = v_t + Wh2 * o_{t-2}. 128 WGs x 512 thr (r6 geometry: r8 proved the
// 1024-thr consolidation regresses -- per-CU ring bytes unchanged, deeper
// reduce). The step is a LATENCY chain; this round shortens the publish path:
//  * per-WAVE flags: producer wave drains only its own ring store via counted
//    s_waitcnt vmcnt(1) (HBM out-store stays in flight) and publishes its own
//    flag -- no WG barrier, no slowest-wave wait, no HBM ack on publish path.
//  * ps double-buffered -> ONE __syncthreads per step (r2-validated pattern).
//  * consumer wave polls its 64 producer (rank,wave) flags with 64 lanes.
//  * ring store: 4 lanes packed into one 8B agent store.
// Arithmetic identical to r6 (fp16 ring values bit-identical).
__global__ __launch_bounds__(512) void rnn_scan_kernel(
    const _Float16* __restrict__ w2,
    short* __restrict__ ring,                // [512][32768] shorts (fp16 bits)
    float* __restrict__ out,
    unsigned* __restrict__ flags)            // [2][64][8][32] uint, 128B/wave-flag
{
    __shared__ float ps[2][8 * 2 * 16 * 17];

    const int j = threadIdx.x;
    const int w = j >> 6, lane = j & 63;
    const int quad = lane >> 4, l15 = lane & 15;
    const int chain = blockIdx.x & 1;
    const int rank = blockIdx.x >> 1;
    const int n0 = rank * 32;

    unsigned* myflag = flags + (((chain * 64 + rank) * 8) + w) * 32;
    // consumer wave w needs producer ranks w*8..w*8+7, all 8 waves each:
    // lane L polls (rank w*8 + (L>>3), wave L&7)
    const unsigned* mypoll = flags + ((chain * 64 + (w * 8 + (lane >> 3))) * 8 + (lane & 7)) * 32;

    halfx8 af[2][8];
#pragma unroll
    for (int gt = 0; gt < 2; ++gt)
#pragma unroll
        for (int c = 0; c < 8; ++c) {
            int row = n0 + gt * 16 + l15;
            int k = w * 256 + c * 32 + quad * 8;
            af[gt][c] = *(const halfx8*)(w2 + (size_t)row * HDIM + k);
        }

    const int rn = j & 31, rb = j >> 5;
    const int gt_r = rn >> 4, row_r = rn & 15;

    for (int s = 0; s < 256; ++s) {
        const int t = chain + 2 * s;
        short* slot_next = ring + (size_t)(s * 2 + chain) * 32768;

        // prefetch v (overlaps poll latency)
        float uv = out[(size_t)rb * TH + (size_t)t * HDIM + n0 + rn];

        floatx4 acc[2][2] = {};
        if (s > 0) {
            const short* slot_prev = ring + (size_t)((s - 1) * 2 + chain) * 32768;
            // 64-lane poll on 64 producer wave-flags
            for (;;) {
                unsigned f = __hip_atomic_load(mypoll, __ATOMIC_RELAXED, __HIP_MEMORY_SCOPE_AGENT);
                if (__all((int)(f >= (unsigned)s))) break;
            }
            __asm__ __volatile__("" ::: "memory");

#pragma unroll
            for (int c = 0; c < 8; ++c) {
                int kg = w * 32 + c * 4 + quad;
                halfx8 bh = *(const halfx8*)(slot_prev + kg * 128 + l15 * 8);
                int cp = c & 1;
                acc[0][cp] = __builtin_amdgcn_mfma_f32_16x16x32_f16(af[0][c], bh, acc[0][cp], 0, 0, 0);
                acc[1][cp] = __builtin_amdgcn_mfma_f32_16x16x32_f16(af[1][c], bh, acc[1][cp], 0, 0, 0);
            }
        }

        floatx4 a0 = acc[0][0] + acc[0][1];
        floatx4 a1 = acc[1][0] + acc[1][1];
        float* psb = ps[s & 1];
#pragma unroll
        for (int r = 0; r < 4; ++r) {
            psb[((w * 2 + 0) * 16 + quad * 4 + r) * 17 + l15] = a0[r];
            psb[((w * 2 + 1) * 16 + quad * 4 + r) * 17 + l15] = a1[r];
        }
        __syncthreads();   // the ONLY barrier per step (ps write -> ps read)

        float sv_f = uv;
#pragma unroll
        for (int ww = 0; ww < 8; ++ww)
            sv_f += psb[((ww * 2 + gt_r) * 16 + row_r) * 17 + rb];

        int n = n0 + rn;

        // fp16 cast; pack 4 lanes -> one 8B relaxed agent store
        unsigned hb = f16bits(sv_f);
        unsigned h1 = __shfl_down(hb, 1);
        unsigned h2 = __shfl_down(hb, 2);
        unsigned h3 = __shfl_down(hb, 3);
        if ((j & 3) == 0) {
            int idx = (n >> 3) * 128 + rb * 8 + (n & 7);  // n&3==0 -> 8B aligned
            ull pk = (ull)(hb | (h1 << 16)) | (((ull)(h2 | (h3 << 16))) << 32);
            __hip_atomic_store((ull*)(slot_next + idx), pk,
                               __ATOMIC_RELAXED, __HIP_MEMORY_SCOPE_AGENT);
        }
        // out store issued now; counted wait lets it stay in flight while the
        // ring store (older) must have drained before the flag goes out.
        out[(size_t)rb * TH + (size_t)t * HDIM + n] = sv_f;
        __asm__ __volatile__("s_waitcnt vmcnt(1)" ::: "memory");
        if (lane == 0)
            __hip_atomic_store(myflag, (unsigned)(s + 1), __ATOMIC_RELAXED, __HIP_MEMORY_SCOPE_AGENT);

        if (t == TLEN - 1) out[(size_t)OUT_MAIN + (size_t)rb * HDIM + n] = sv_f;
    }
}

// ---------------- launcher ----------------
extern "C" void kernel_launch(void* const* d_in, const int* in_sizes, int n_in,
                              void* d_out, int out_size, void* d_ws, size_t ws_size,
                              hipStream_t stream) {
    (void)in_sizes; (void)n_in; (void)out_size; (void)ws_size;
    const float* x    = (const float*)d_in[0];
    const float* W    = (const float*)d_in[1];
    const float* bias = (const float*)d_in[2];
    float* out = (float*)d_out;
    char* ws = (char*)d_ws;

    // Memory plan (80.0 MB + 128KB flags; fp16 single-plane everywhere):
    //  xh   [0,32M)   fp16 x          (dead after gemm_u)
    //  whT  [0,8M)    fp16 Wh^T       (transpose after gemm_u; dead after gemm_w2)
    //  w2   [8,16M)   fp16 Wh^2       (gemm_w2 -> scan)
    //  ring [16,48M)  512 slots x 64KB (scan only; aliases dead xh tail/wxh/whh)
    //  wxh  [32,40M)  fp16 Wx         (dead after gemm_u)
    //  whh  [40,48M)  fp16 Wh         (dead after gemm_w2)
    //  uh   [48,80M)  fp16 u          (dead after gemm_v)
    //  flags [80M,+128K)  [2][64][8][32] uint wave-flags
    _Float16* xh  = (_Float16*)(ws);
    _Float16* whT = (_Float16*)(ws);
    _Float16* w2  = (_Float16*)(ws + 8388608);
    short*    ring = (short*)(ws + 16777216);
    _Float16* wxh = (_Float16*)(ws + 33554432);
    _Float16* whh = (_Float16*)(ws + 41943040);
    _Float16* uh  = (_Float16*)(ws + 50331648);
    unsigned* flags = (unsigned*)(ws + 83886080);

    hipMemsetAsync(ws + 83886080, 0, 131072, stream);

    cast_x_kernel<<<8192, 256, 0, stream>>>(x, xh, OUT_MAIN);
    cast_w_kernel<<<8192, 256, 0, stream>>>(W, wxh, whh);
    gemm_u_kernel<<<dim3(64, 16), 256, 0, stream>>>(xh, wxh, bias, out, uh);
    transpose_wh_kernel<<<dim3(64, 64), dim3(32, 8), 0, stream>>>(W, whT);
    gemm_v_kernel<<<dim3(64, 16), 256, 0, stream>>>(uh, whh, out);
    gemm_w2_kernel<<<dim3(16, 16), 256, 0, stream>>>(whh, whT, w2);
    rnn_scan_kernel<<<128, 512, 0, stream>>>(w2, ring, out, flags);
}

// Round 11
// 1309.704 us; speedup vs baseline: 1.0003x; 1.0003x over previous
//
#include <hip/hip_runtime.h>
#include <hip/hip_fp16.h>
#include <stdint.h>

#define HDIM 2048
#define BATCH 16
#define TLEN 512
#define TH   1048576        // TLEN*HDIM
#define OUT_MAIN 16777216   // BATCH*TLEN*HDIM

using floatx4 = __attribute__((ext_vector_type(4))) float;
using shortx8 = __attribute__((ext_vector_type(8))) short;
using halfx8  = __attribute__((ext_vector_type(8))) _Float16;
typedef unsigned long long ull;

static __device__ __forceinline__ unsigned f16bits(float f) {
    _Float16 h = (_Float16)f;
    return (unsigned)*(unsigned short*)&h;
}

// ---------------- cast kernels ----------------
__global__ void cast_x_kernel(const float* __restrict__ x, _Float16* __restrict__ xh, int n) {
    int i = blockIdx.x * blockDim.x + threadIdx.x;
    int stride = gridDim.x * blockDim.x;
    for (; i < n; i += stride) xh[i] = (_Float16)x[i];
}

__global__ void cast_w_kernel(const float* __restrict__ W,
                              _Float16* __restrict__ wxh,
                              _Float16* __restrict__ whh) {
    int i = blockIdx.x * blockDim.x + threadIdx.x;
    int stride = gridDim.x * blockDim.x;
    for (; i < HDIM * HDIM; i += stride) {
        int g = i >> 11, k = i & (HDIM - 1);
        wxh[i] = (_Float16)W[g * (2 * HDIM) + k];
        whh[i] = (_Float16)W[g * (2 * HDIM) + HDIM + k];
    }
}

// Transpose Wh -> whT (fp16). Runs after gemm_u; output aliases dead xh.
__global__ void transpose_wh_kernel(const float* __restrict__ W,
                                    _Float16* __restrict__ whT) {
    __shared__ float tile[32][33];
    int bx = blockIdx.x * 32, by = blockIdx.y * 32;
    int tx = threadIdx.x, ty = threadIdx.y;  // (32,8)
#pragma unroll
    for (int r = 0; r < 32; r += 8)
        tile[ty + r][tx] = W[(size_t)(by + ty + r) * (2 * HDIM) + HDIM + bx + tx];
    __syncthreads();
#pragma unroll
    for (int r = 0; r < 32; r += 8)
        whT[(size_t)(bx + ty + r) * HDIM + by + tx] = (_Float16)tile[tx][ty + r];
}

// ---------------- phase A: u = x @ Wx^T + b -> out (fp32) + uh (fp16) ----------------
__global__ __launch_bounds__(256) void gemm_u_kernel(
    const _Float16* __restrict__ xh,
    const _Float16* __restrict__ wxh,
    const float* __restrict__ bias,
    float* __restrict__ out,
    _Float16* __restrict__ uh)
{
    __shared__ __align__(16) short As[4 * 128 * 8];
    __shared__ __align__(16) short Bs[4 * 128 * 8];

    const int j = threadIdx.x;
    const int m0 = blockIdx.x * 128;
    const int n0 = blockIdx.y * 128;
    const int w = j >> 6, lane = j & 63;
    const int wm = (w >> 1) * 64, wn = (w & 1) * 64;
    const int quad = lane >> 4, l15 = lane & 15;

    const int mA0 = j & 127, kg0 = j >> 7;
    const int mA1 = (j + 256) & 127, kg1 = (j + 256) >> 7;

    floatx4 acc[4][4] = {};

    shortx8 ra0 = *(const shortx8*)(xh  + (size_t)(m0 + mA0) * HDIM + kg0 * 8);
    shortx8 ra1 = *(const shortx8*)(xh  + (size_t)(m0 + mA1) * HDIM + kg1 * 8);
    shortx8 rb0 = *(const shortx8*)(wxh + (size_t)(n0 + mA0) * HDIM + kg0 * 8);
    shortx8 rb1 = *(const shortx8*)(wxh + (size_t)(n0 + mA1) * HDIM + kg1 * 8);

    for (int kt = 0; kt < 64; ++kt) {
        ((shortx8*)As)[kg0 * 128 + mA0] = ra0;
        ((shortx8*)As)[kg1 * 128 + mA1] = ra1;
        ((shortx8*)Bs)[kg0 * 128 + mA0] = rb0;
        ((shortx8*)Bs)[kg1 * 128 + mA1] = rb1;
        __syncthreads();

        if (kt < 63) {
            int k = (kt + 1) * 32;
            ra0 = *(const shortx8*)(xh  + (size_t)(m0 + mA0) * HDIM + k + kg0 * 8);
            ra1 = *(const shortx8*)(xh  + (size_t)(m0 + mA1) * HDIM + k + kg1 * 8);
            rb0 = *(const shortx8*)(wxh + (size_t)(n0 + mA0) * HDIM + k + kg0 * 8);
            rb1 = *(const shortx8*)(wxh + (size_t)(n0 + mA1) * HDIM + k + kg1 * 8);
        }

        halfx8 af[4], bf[4];
#pragma unroll
        for (int mt = 0; mt < 4; ++mt)
            af[mt] = ((const halfx8*)As)[quad * 128 + wm + mt * 16 + l15];
#pragma unroll
        for (int nt = 0; nt < 4; ++nt)
            bf[nt] = ((const halfx8*)Bs)[quad * 128 + wn + nt * 16 + l15];
#pragma unroll
        for (int mt = 0; mt < 4; ++mt)
#pragma unroll
            for (int nt = 0; nt < 4; ++nt)
                acc[mt][nt] = __builtin_amdgcn_mfma_f32_16x16x32_f16(af[mt], bf[nt], acc[mt][nt], 0, 0, 0);
        __syncthreads();
    }

#pragma unroll
    for (int nt = 0; nt < 4; ++nt) {
        int gn = n0 + wn + nt * 16 + l15;
        float bv = bias[gn];
#pragma unroll
        for (int mt = 0; mt < 4; ++mt) {
#pragma unroll
            for (int r = 0; r < 4; ++r) {
                int gm = m0 + wm + mt * 16 + quad * 4 + r;
                float v = acc[mt][nt][r] + bv;
                out[(size_t)gm * HDIM + gn] = v;
                uh[(size_t)gm * HDIM + gn] = (_Float16)v;
            }
        }
    }
}

// ---------------- Wh2 = Wh*Wh (fp16 single-plane) ----------------
__global__ __launch_bounds__(256) void gemm_w2_kernel(
    const _Float16* __restrict__ whh,
    const _Float16* __restrict__ wT,
    _Float16* __restrict__ w2)
{
    __shared__ __align__(16) short As[4 * 128 * 8];
    __shared__ __align__(16) short Bs[4 * 128 * 8];

    const int j = threadIdx.x;
    const int m0 = blockIdx.x * 128;
    const int n0 = blockIdx.y * 128;
    const int w = j >> 6, lane = j & 63;
    const int wm = (w >> 1) * 64, wn = (w & 1) * 64;
    const int quad = lane >> 4, l15 = lane & 15;

    const int mA0 = j & 127, kg0 = j >> 7;
    const int mA1 = (j + 256) & 127, kg1 = (j + 256) >> 7;

    floatx4 acc[4][4] = {};

    shortx8 ra0 = *(const shortx8*)(whh + (size_t)(m0 + mA0) * HDIM + kg0 * 8);
    shortx8 ra1 = *(const shortx8*)(whh + (size_t)(m0 + mA1) * HDIM + kg1 * 8);
    shortx8 rb0 = *(const shortx8*)(wT  + (size_t)(n0 + mA0) * HDIM + kg0 * 8);
    shortx8 rb1 = *(const shortx8*)(wT  + (size_t)(n0 + mA1) * HDIM + kg1 * 8);

    for (int kt = 0; kt < 64; ++kt) {
        ((shortx8*)As)[kg0 * 128 + mA0] = ra0;
        ((shortx8*)As)[kg1 * 128 + mA1] = ra1;
        ((shortx8*)Bs)[kg0 * 128 + mA0] = rb0;
        ((shortx8*)Bs)[kg1 * 128 + mA1] = rb1;
        __syncthreads();

        if (kt < 63) {
            int k = (kt + 1) * 32;
            ra0 = *(const shortx8*)(whh + (size_t)(m0 + mA0) * HDIM + k + kg0 * 8);
            ra1 = *(const shortx8*)(whh + (size_t)(m0 + mA1) * HDIM + k + kg1 * 8);
            rb0 = *(const shortx8*)(wT  + (size_t)(n0 + mA0) * HDIM + k + kg0 * 8);
            rb1 = *(const shortx8*)(wT  + (size_t)(n0 + mA1) * HDIM + k + kg1 * 8);
        }

        halfx8 af[4], bf[4];
#pragma unroll
        for (int mt = 0; mt < 4; ++mt)
            af[mt] = ((const halfx8*)As)[quad * 128 + wm + mt * 16 + l15];
#pragma unroll
        for (int nt = 0; nt < 4; ++nt)
            bf[nt] = ((const halfx8*)Bs)[quad * 128 + wn + nt * 16 + l15];
#pragma unroll
        for (int mt = 0; mt < 4; ++mt)
#pragma unroll
            for (int nt = 0; nt < 4; ++nt)
                acc[mt][nt] = __builtin_amdgcn_mfma_f32_16x16x32_f16(af[mt], bf[nt], acc[mt][nt], 0, 0, 0);
        __syncthreads();
    }

#pragma unroll
    for (int nt = 0; nt < 4; ++nt) {
        int gn = n0 + wn + nt * 16 + l15;
#pragma unroll
        for (int mt = 0; mt < 4; ++mt)
#pragma unroll
            for (int r = 0; r < 4; ++r) {
                int gm = m0 + wm + mt * 16 + quad * 4 + r;
                w2[(size_t)gm * HDIM + gn] = (_Float16)acc[mt][nt][r];
            }
    }
}

// ---------------- v = u + Wh*u_shift (fp16; t==0 rows keep u) ----------------
__global__ __launch_bounds__(256) void gemm_v_kernel(
    const _Float16* __restrict__ uh,
    const _Float16* __restrict__ whh,
    float* __restrict__ out)
{
    __shared__ __align__(16) short As[4 * 128 * 8];
    __shared__ __align__(16) short Bs[4 * 128 * 8];

    const int j = threadIdx.x;
    const int m0 = blockIdx.x * 128;
    const int n0 = blockIdx.y * 128;
    const int w = j >> 6, lane = j & 63;
    const int wm = (w >> 1) * 64, wn = (w & 1) * 64;
    const int quad = lane >> 4, l15 = lane & 15;

    const int mA0 = j & 127, kg0 = j >> 7;
    const int mA1 = (j + 256) & 127, kg1 = (j + 256) >> 7;

    int rowA0 = m0 + mA0 - 1; if (rowA0 < 0) rowA0 = 0;
    int rowA1 = m0 + mA1 - 1; if (rowA1 < 0) rowA1 = 0;

    floatx4 acc[4][4] = {};

    shortx8 ra0 = *(const shortx8*)(uh  + (size_t)rowA0 * HDIM + kg0 * 8);
    shortx8 ra1 = *(const shortx8*)(uh  + (size_t)rowA1 * HDIM + kg1 * 8);
    shortx8 rb0 = *(const shortx8*)(whh + (size_t)(n0 + mA0) * HDIM + kg0 * 8);
    shortx8 rb1 = *(const shortx8*)(whh + (size_t)(n0 + mA1) * HDIM + kg1 * 8);

    for (int kt = 0; kt < 64; ++kt) {
        ((shortx8*)As)[kg0 * 128 + mA0] = ra0;
        ((shortx8*)As)[kg1 * 128 + mA1] = ra1;
        ((shortx8*)Bs)[kg0 * 128 + mA0] = rb0;
        ((shortx8*)Bs)[kg1 * 128 + mA1] = rb1;
        __syncthreads();

        if (kt < 63) {
            int k = (kt + 1) * 32;
            ra0 = *(const shortx8*)(uh  + (size_t)rowA0 * HDIM + k + kg0 * 8);
            ra1 = *(const shortx8*)(uh  + (size_t)rowA1 * HDIM + k + kg1 * 8);
            rb0 = *(const shortx8*)(whh + (size_t)(n0 + mA0) * HDIM + k + kg0 * 8);
            rb1 = *(const shortx8*)(whh + (size_t)(n0 + mA1) * HDIM + k + kg1 * 8);
        }

        halfx8 af[4], bf[4];
#pragma unroll
        for (int mt = 0; mt < 4; ++mt)
            af[mt] = ((const halfx8*)As)[quad * 128 + wm + mt * 16 + l15];
#pragma unroll
        for (int nt = 0; nt < 4; ++nt)
            bf[nt] = ((const halfx8*)Bs)[quad * 128 + wn + nt * 16 + l15];
#pragma unroll
        for (int mt = 0; mt < 4; ++mt)
#pragma unroll
            for (int nt = 0; nt < 4; ++nt)
                acc[mt][nt] = __builtin_amdgcn_mfma_f32_16x16x32_f16(af[mt], bf[nt], acc[mt][nt], 0, 0, 0);
        __syncthreads();
    }

#pragma unroll
    for (int nt = 0; nt < 4; ++nt) {
        int gn = n0 + wn + nt * 16 + l15;
#pragma unroll
        for (int mt = 0; mt < 4; ++mt)
#pragma unroll
            for (int r = 0; r < 4; ++r) {
                int gm = m0 + wm + mt * 16 + quad * 4 + r;
                float uval = out[(size_t)gm * HDIM + gn];
                float res = ((gm & 511) == 0) ? uval : (acc[mt][nt][r] + uval);
                out[(size_t)gm * HDIM + gn] = res;
            }
    }
}

// ---------------- phase B: two parity chains, fp16 ring, BATCH-SPLIT partition ----------------
// o_t = v_t + Wh2 * o_{t-2}. 128 WGs x 512 thr, r6 sync protocol VERBATIM
// (8-line poll was optimal; r10's 64-line wave-flags regressed 497->797).
// NEW: rank = (bg, cg): each WG owns 64 cols x 8 batches (was 32 cols x 16).
// Per-WG ring read HALVES to 32KB/step (only its batch-group's half of the
// slot) -- the measured per-WG-fetch term (~33 GB/s/CU effective) is the
// dominant step cost. Weights double to af[4][8] (128 VGPR/lane, <256 cap).
// MFMA N carries 8 real batches + 8 dups (lanes 8-15 mirror 0-7; coalescer
// merges dup loads). Wave w's K-slice (256 cols) <- col-groups 4w..4w+3 of
// the same bg -> poll 4 flags/wave. Slot layout: [batch][2048] fp16.
__global__ __launch_bounds__(512, 2) void rnn_scan_kernel(
    const _Float16* __restrict__ w2,
    short* __restrict__ ring,                // [512][32768] shorts: [16][2048] fp16
    float* __restrict__ out,
    unsigned* __restrict__ flags)            // [2][64][32] uint, 128B stride
{
    __shared__ float ps[8 * 4 * 16 * 9];     // [wave][gt][colrow][8+1]

    const int j = threadIdx.x;
    const int w = j >> 6, lane = j & 63;
    const int quad = lane >> 4, l15 = lane & 15;
    const int chain = blockIdx.x & 1;
    const int rank = blockIdx.x >> 1;        // 0..63
    const int bg = rank >> 5;                // batch-group (8 batches)
    const int cg = rank & 31;                // col-group (64 cols)
    const int n0 = cg * 64;
    const int b0 = bg * 8;

    unsigned* myflag = flags + (chain * 64 + rank) * 32;
    const unsigned* pollbase = flags + chain * 64 * 32;

    // Wh2 slice: 64 cols (4 gt tiles), wave K-slice w*256..+256 (8 chunks of 32)
    halfx8 af[4][8];
#pragma unroll
    for (int gt = 0; gt < 4; ++gt)
#pragma unroll
        for (int c = 0; c < 8; ++c) {
            int row = n0 + gt * 16 + l15;
            int k = w * 256 + c * 32 + quad * 8;
            af[gt][c] = *(const halfx8*)(w2 + (size_t)row * HDIM + k);
        }

    const int col_r = j & 63, b_r = j >> 6;  // reduce mapping: col 0..63, batch 0..7
    const int gt_r = col_r >> 4, row_r = col_r & 15;
    const int mybatch = b0 + (l15 & 7);      // B-operand batch (lanes 8-15 dup 0-7)

    for (int s = 0; s < 256; ++s) {
        const int t = chain + 2 * s;
        short* slot_next = ring + (size_t)(s * 2 + chain) * 32768;

        // prefetch v (overlaps poll latency)
        float uv = out[(size_t)(b0 + b_r) * TH + (size_t)t * HDIM + n0 + col_r];

        floatx4 acc[4][2] = {};
        if (s > 0) {
            const short* slot_prev = ring + (size_t)((s - 1) * 2 + chain) * 32768;
            // wave w needs col-groups 4w..4w+3 of its own batch-group: 4 flags
            if (lane < 4) {
                const unsigned* fp = pollbase + (bg * 32 + w * 4 + lane) * 32;
                while (__hip_atomic_load(fp, __ATOMIC_RELAXED, __HIP_MEMORY_SCOPE_AGENT) < (unsigned)s) {}
            }
            __asm__ __volatile__("" ::: "memory");

#pragma unroll
            for (int c = 0; c < 8; ++c) {
                halfx8 bh = *(const halfx8*)(slot_prev + mybatch * 2048 + w * 256 + c * 32 + quad * 8);
                int cp = c & 1;
                acc[0][cp] = __builtin_amdgcn_mfma_f32_16x16x32_f16(af[0][c], bh, acc[0][cp], 0, 0, 0);
                acc[1][cp] = __builtin_amdgcn_mfma_f32_16x16x32_f16(af[1][c], bh, acc[1][cp], 0, 0, 0);
                acc[2][cp] = __builtin_amdgcn_mfma_f32_16x16x32_f16(af[2][c], bh, acc[2][cp], 0, 0, 0);
                acc[3][cp] = __builtin_amdgcn_mfma_f32_16x16x32_f16(af[3][c], bh, acc[3][cp], 0, 0, 0);
            }
        }

#pragma unroll
        for (int gt = 0; gt < 4; ++gt) {
            floatx4 a = acc[gt][0] + acc[gt][1];
            if (l15 < 8) {
#pragma unroll
                for (int r = 0; r < 4; ++r)
                    ps[((w * 4 + gt) * 16 + quad * 4 + r) * 9 + l15] = a[r];
            }
        }
        __syncthreads();

        float sv_f = uv;
#pragma unroll
        for (int ww = 0; ww < 8; ++ww)
            sv_f += ps[((ww * 4 + gt_r) * 16 + row_r) * 9 + b_r];

        // fp16 cast; pack 4 adjacent cols (same batch) -> one 8B agent store
        unsigned hb = f16bits(sv_f);
        unsigned h1 = __shfl_down(hb, 1);
        unsigned h2 = __shfl_down(hb, 2);
        unsigned h3 = __shfl_down(hb, 3);
        if ((j & 3) == 0) {
            size_t idx = (size_t)(b0 + b_r) * 2048 + n0 + col_r;  // col_r%4==0 -> 8B aligned
            ull pk = (ull)(hb | (h1 << 16)) | (((ull)(h2 | (h3 << 16))) << 32);
            __hip_atomic_store((ull*)(slot_next + idx), pk,
                               __ATOMIC_RELAXED, __HIP_MEMORY_SCOPE_AGENT);
        }

        // barrier drains ring stores (vmcnt(0) before s_barrier), then publish
        __syncthreads();
        if (j == 0)
            __hip_atomic_store(myflag, (unsigned)(s + 1), __ATOMIC_RELAXED, __HIP_MEMORY_SCOPE_AGENT);

        // out stores AFTER the flag: off the inter-WG critical path
        out[(size_t)(b0 + b_r) * TH + (size_t)t * HDIM + n0 + col_r] = sv_f;
        if (t == TLEN - 1) out[(size_t)OUT_MAIN + (size_t)(b0 + b_r) * HDIM + n0 + col_r] = sv_f;
    }
}

// ---------------- launcher ----------------
extern "C" void kernel_launch(void* const* d_in, const int* in_sizes, int n_in,
                              void* d_out, int out_size, void* d_ws, size_t ws_size,
                              hipStream_t stream) {
    (void)in_sizes; (void)n_in; (void)out_size; (void)ws_size;
    const float* x    = (const float*)d_in[0];
    const float* W    = (const float*)d_in[1];
    const float* bias = (const float*)d_in[2];
    float* out = (float*)d_out;
    char* ws = (char*)d_ws;

    // Memory plan (80.0 MB + 16KB flags; fp16 single-plane everywhere):
    //  xh   [0,32M)   fp16 x          (dead after gemm_u)
    //  whT  [0,8M)    fp16 Wh^T       (transpose after gemm_u; dead after gemm_w2)
    //  w2   [8,16M)   fp16 Wh^2       (gemm_w2 -> scan)
    //  ring [16,48M)  512 slots x 64KB (scan only; aliases dead xh tail/wxh/whh)
    //  wxh  [32,40M)  fp16 Wx         (dead after gemm_u)
    //  whh  [40,48M)  fp16 Wh         (dead after gemm_w2)
    //  uh   [48,80M)  fp16 u          (dead after gemm_v)
    //  flags [80M,+16K)
    _Float16* xh  = (_Float16*)(ws);
    _Float16* whT = (_Float16*)(ws);
    _Float16* w2  = (_Float16*)(ws + 8388608);
    short*    ring = (short*)(ws + 16777216);
    _Float16* wxh = (_Float16*)(ws + 33554432);
    _Float16* whh = (_Float16*)(ws + 41943040);
    _Float16* uh  = (_Float16*)(ws + 50331648);
    unsigned* flags = (unsigned*)(ws + 83886080);

    hipMemsetAsync(ws + 83886080, 0, 16384, stream);

    cast_x_kernel<<<8192, 256, 0, stream>>>(x, xh, OUT_MAIN);
    cast_w_kernel<<<8192, 256, 0, stream>>>(W, wxh, whh);
    gemm_u_kernel<<<dim3(64, 16), 256, 0, stream>>>(xh, wxh, bias, out, uh);
    transpose_wh_kernel<<<dim3(64, 64), dim3(32, 8), 0, stream>>>(W, whT);
    gemm_v_kernel<<<dim3(64, 16), 256, 0, stream>>>(uh, whh, out);
    gemm_w2_kernel<<<dim3(16, 16), 256, 0, stream>>>(whh, whT, w2);
    rnn_scan_kernel<<<128, 512, 0, stream>>>(w2, ring, out, flags);
}

// Round 13
// 1006.436 us; speedup vs baseline: 1.3017x; 1.3013x over previous
//
#include <hip/hip_runtime.h>
#include <hip/hip_fp16.h>
#include <stdint.h>

#define HDIM 2048
#define BATCH 16
#define TLEN 512
#define TH   1048576        // TLEN*HDIM
#define OUT_MAIN 16777216   // BATCH*TLEN*HDIM

using floatx4 = __attribute__((ext_vector_type(4))) float;
using shortx8 = __attribute__((ext_vector_type(8))) short;
using halfx8  = __attribute__((ext_vector_type(8))) _Float16;
typedef unsigned long long ull;

static __device__ __forceinline__ unsigned f16bits(float f) {
    _Float16 h = (_Float16)f;
    return (unsigned)*(unsigned short*)&h;
}

// ---------------- cast kernels ----------------
__global__ void cast_x_kernel(const float* __restrict__ x, _Float16* __restrict__ xh, int n) {
    int i = blockIdx.x * blockDim.x + threadIdx.x;
    int stride = gridDim.x * blockDim.x;
    for (; i < n; i += stride) xh[i] = (_Float16)x[i];
}

__global__ void cast_w_kernel(const float* __restrict__ W,
                              _Float16* __restrict__ wxh,
                              _Float16* __restrict__ whh) {
    int i = blockIdx.x * blockDim.x + threadIdx.x;
    int stride = gridDim.x * blockDim.x;
    for (; i < HDIM * HDIM; i += stride) {
        int g = i >> 11, k = i & (HDIM - 1);
        wxh[i] = (_Float16)W[g * (2 * HDIM) + k];
        whh[i] = (_Float16)W[g * (2 * HDIM) + HDIM + k];
    }
}

// Transpose Wh -> whT (fp16). Runs after gemm_u; output aliases dead xh.
__global__ void transpose_wh_kernel(const float* __restrict__ W,
                                    _Float16* __restrict__ whT) {
    __shared__ float tile[32][33];
    int bx = blockIdx.x * 32, by = blockIdx.y * 32;
    int tx = threadIdx.x, ty = threadIdx.y;  // (32,8)
#pragma unroll
    for (int r = 0; r < 32; r += 8)
        tile[ty + r][tx] = W[(size_t)(by + ty + r) * (2 * HDIM) + HDIM + bx + tx];
    __syncthreads();
#pragma unroll
    for (int r = 0; r < 32; r += 8)
        whT[(size_t)(bx + ty + r) * HDIM + by + tx] = (_Float16)tile[tx][ty + r];
}

// ---------------- phase A: u = x @ Wx^T + b -> out (fp32) + uh (fp16) ----------------
__global__ __launch_bounds__(256) void gemm_u_kernel(
    const _Float16* __restrict__ xh,
    const _Float16* __restrict__ wxh,
    const float* __restrict__ bias,
    float* __restrict__ out,
    _Float16* __restrict__ uh)
{
    __shared__ __align__(16) short As[4 * 128 * 8];
    __shared__ __align__(16) short Bs[4 * 128 * 8];

    const int j = threadIdx.x;
    const int m0 = blockIdx.x * 128;
    const int n0 = blockIdx.y * 128;
    const int w = j >> 6, lane = j & 63;
    const int wm = (w >> 1) * 64, wn = (w & 1) * 64;
    const int quad = lane >> 4, l15 = lane & 15;

    const int mA0 = j & 127, kg0 = j >> 7;
    const int mA1 = (j + 256) & 127, kg1 = (j + 256) >> 7;

    floatx4 acc[4][4] = {};

    shortx8 ra0 = *(const shortx8*)(xh  + (size_t)(m0 + mA0) * HDIM + kg0 * 8);
    shortx8 ra1 = *(const shortx8*)(xh  + (size_t)(m0 + mA1) * HDIM + kg1 * 8);
    shortx8 rb0 = *(const shortx8*)(wxh + (size_t)(n0 + mA0) * HDIM + kg0 * 8);
    shortx8 rb1 = *(const shortx8*)(wxh + (size_t)(n0 + mA1) * HDIM + kg1 * 8);

    for (int kt = 0; kt < 64; ++kt) {
        ((shortx8*)As)[kg0 * 128 + mA0] = ra0;
        ((shortx8*)As)[kg1 * 128 + mA1] = ra1;
        ((shortx8*)Bs)[kg0 * 128 + mA0] = rb0;
        ((shortx8*)Bs)[kg1 * 128 + mA1] = rb1;
        __syncthreads();

        if (kt < 63) {
            int k = (kt + 1) * 32;
            ra0 = *(const shortx8*)(xh  + (size_t)(m0 + mA0) * HDIM + k + kg0 * 8);
            ra1 = *(const shortx8*)(xh  + (size_t)(m0 + mA1) * HDIM + k + kg1 * 8);
            rb0 = *(const shortx8*)(wxh + (size_t)(n0 + mA0) * HDIM + k + kg0 * 8);
            rb1 = *(const shortx8*)(wxh + (size_t)(n0 + mA1) * HDIM + k + kg1 * 8);
        }

        halfx8 af[4], bf[4];
#pragma unroll
        for (int mt = 0; mt < 4; ++mt)
            af[mt] = ((const halfx8*)As)[quad * 128 + wm + mt * 16 + l15];
#pragma unroll
        for (int nt = 0; nt < 4; ++nt)
            bf[nt] = ((const halfx8*)Bs)[quad * 128 + wn + nt * 16 + l15];
#pragma unroll
        for (int mt = 0; mt < 4; ++mt)
#pragma unroll
            for (int nt = 0; nt < 4; ++nt)
                acc[mt][nt] = __builtin_amdgcn_mfma_f32_16x16x32_f16(af[mt], bf[nt], acc[mt][nt], 0, 0, 0);
        __syncthreads();
    }

#pragma unroll
    for (int nt = 0; nt < 4; ++nt) {
        int gn = n0 + wn + nt * 16 + l15;
        float bv = bias[gn];
#pragma unroll
        for (int mt = 0; mt < 4; ++mt) {
#pragma unroll
            for (int r = 0; r < 4; ++r) {
                int gm = m0 + wm + mt * 16 + quad * 4 + r;
                float v = acc[mt][nt][r] + bv;
                out[(size_t)gm * HDIM + gn] = v;
                uh[(size_t)gm * HDIM + gn] = (_Float16)v;
            }
        }
    }
}

// ---------------- Wh2 = Wh*Wh (fp16 single-plane) ----------------
__global__ __launch_bounds__(256) void gemm_w2_kernel(
    const _Float16* __restrict__ whh,
    const _Float16* __restrict__ wT,
    _Float16* __restrict__ w2)
{
    __shared__ __align__(16) short As[4 * 128 * 8];
    __shared__ __align__(16) short Bs[4 * 128 * 8];

    const int j = threadIdx.x;
    const int m0 = blockIdx.x * 128;
    const int n0 = blockIdx.y * 128;
    const int w = j >> 6, lane = j & 63;
    const int wm = (w >> 1) * 64, wn = (w & 1) * 64;
    const int quad = lane >> 4, l15 = lane & 15;

    const int mA0 = j & 127, kg0 = j >> 7;
    const int mA1 = (j + 256) & 127, kg1 = (j + 256) >> 7;

    floatx4 acc[4][4] = {};

    shortx8 ra0 = *(const shortx8*)(whh + (size_t)(m0 + mA0) * HDIM + kg0 * 8);
    shortx8 ra1 = *(const shortx8*)(whh + (size_t)(m0 + mA1) * HDIM + kg1 * 8);
    shortx8 rb0 = *(const shortx8*)(wT  + (size_t)(n0 + mA0) * HDIM + kg0 * 8);
    shortx8 rb1 = *(const shortx8*)(wT  + (size_t)(n0 + mA1) * HDIM + kg1 * 8);

    for (int kt = 0; kt < 64; ++kt) {
        ((shortx8*)As)[kg0 * 128 + mA0] = ra0;
        ((shortx8*)As)[kg1 * 128 + mA1] = ra1;
        ((shortx8*)Bs)[kg0 * 128 + mA0] = rb0;
        ((shortx8*)Bs)[kg1 * 128 + mA1] = rb1;
        __syncthreads();

        if (kt < 63) {
            int k = (kt + 1) * 32;
            ra0 = *(const shortx8*)(whh + (size_t)(m0 + mA0) * HDIM + k + kg0 * 8);
            ra1 = *(const shortx8*)(whh + (size_t)(m0 + mA1) * HDIM + k + kg1 * 8);
            rb0 = *(const shortx8*)(wT  + (size_t)(n0 + mA0) * HDIM + k + kg0 * 8);
            rb1 = *(const shortx8*)(wT  + (size_t)(n0 + mA1) * HDIM + k + kg1 * 8);
        }

        halfx8 af[4], bf[4];
#pragma unroll
        for (int mt = 0; mt < 4; ++mt)
            af[mt] = ((const halfx8*)As)[quad * 128 + wm + mt * 16 + l15];
#pragma unroll
        for (int nt = 0; nt < 4; ++nt)
            bf[nt] = ((const halfx8*)Bs)[quad * 128 + wn + nt * 16 + l15];
#pragma unroll
        for (int mt = 0; mt < 4; ++mt)
#pragma unroll
            for (int nt = 0; nt < 4; ++nt)
                acc[mt][nt] = __builtin_amdgcn_mfma_f32_16x16x32_f16(af[mt], bf[nt], acc[mt][nt], 0, 0, 0);
        __syncthreads();
    }

#pragma unroll
    for (int nt = 0; nt < 4; ++nt) {
        int gn = n0 + wn + nt * 16 + l15;
#pragma unroll
        for (int mt = 0; mt < 4; ++mt)
#pragma unroll
            for (int r = 0; r < 4; ++r) {
                int gm = m0 + wm + mt * 16 + quad * 4 + r;
                w2[(size_t)gm * HDIM + gn] = (_Float16)acc[mt][nt][r];
            }
    }
}

// ---------------- v = u + Wh*u_shift (fp16; t==0 rows keep u) ----------------
__global__ __launch_bounds__(256) void gemm_v_kernel(
    const _Float16* __restrict__ uh,
    const _Float16* __restrict__ whh,
    float* __restrict__ out)
{
    __shared__ __align__(16) short As[4 * 128 * 8];
    __shared__ __align__(16) short Bs[4 * 128 * 8];

    const int j = threadIdx.x;
    const int m0 = blockIdx.x * 128;
    const int n0 = blockIdx.y * 128;
    const int w = j >> 6, lane = j & 63;
    const int wm = (w >> 1) * 64, wn = (w & 1) * 64;
    const int quad = lane >> 4, l15 = lane & 15;

    const int mA0 = j & 127, kg0 = j >> 7;
    const int mA1 = (j + 256) & 127, kg1 = (j + 256) >> 7;

    int rowA0 = m0 + mA0 - 1; if (rowA0 < 0) rowA0 = 0;
    int rowA1 = m0 + mA1 - 1; if (rowA1 < 0) rowA1 = 0;

    floatx4 acc[4][4] = {};

    shortx8 ra0 = *(const shortx8*)(uh  + (size_t)rowA0 * HDIM + kg0 * 8);
    shortx8 ra1 = *(const shortx8*)(uh  + (size_t)rowA1 * HDIM + kg1 * 8);
    shortx8 rb0 = *(const shortx8*)(whh + (size_t)(n0 + mA0) * HDIM + kg0 * 8);
    shortx8 rb1 = *(const shortx8*)(whh + (size_t)(n0 + mA1) * HDIM + kg1 * 8);

    for (int kt = 0; kt < 64; ++kt) {
        ((shortx8*)As)[kg0 * 128 + mA0] = ra0;
        ((shortx8*)As)[kg1 * 128 + mA1] = ra1;
        ((shortx8*)Bs)[kg0 * 128 + mA0] = rb0;
        ((shortx8*)Bs)[kg1 * 128 + mA1] = rb1;
        __syncthreads();

        if (kt < 63) {
            int k = (kt + 1) * 32;
            ra0 = *(const shortx8*)(uh  + (size_t)rowA0 * HDIM + k + kg0 * 8);
            ra1 = *(const shortx8*)(uh  + (size_t)rowA1 * HDIM + k + kg1 * 8);
            rb0 = *(const shortx8*)(whh + (size_t)(n0 + mA0) * HDIM + k + kg0 * 8);
            rb1 = *(const shortx8*)(whh + (size_t)(n0 + mA1) * HDIM + k + kg1 * 8);
        }

        halfx8 af[4], bf[4];
#pragma unroll
        for (int mt = 0; mt < 4; ++mt)
            af[mt] = ((const halfx8*)As)[quad * 128 + wm + mt * 16 + l15];
#pragma unroll
        for (int nt = 0; nt < 4; ++nt)
            bf[nt] = ((const halfx8*)Bs)[quad * 128 + wn + nt * 16 + l15];
#pragma unroll
        for (int mt = 0; mt < 4; ++mt)
#pragma unroll
            for (int nt = 0; nt < 4; ++nt)
                acc[mt][nt] = __builtin_amdgcn_mfma_f32_16x16x32_f16(af[mt], bf[nt], acc[mt][nt], 0, 0, 0);
        __syncthreads();
    }

#pragma unroll
    for (int nt = 0; nt < 4; ++nt) {
        int gn = n0 + wn + nt * 16 + l15;
#pragma unroll
        for (int mt = 0; mt < 4; ++mt)
#pragma unroll
            for (int r = 0; r < 4; ++r) {
                int gm = m0 + wm + mt * 16 + quad * 4 + r;
                float uval = out[(size_t)gm * HDIM + gn];
                float res = ((gm & 511) == 0) ? uval : (acc[mt][nt][r] + uval);
                out[(size_t)gm * HDIM + gn] = res;
            }
    }
}

// ---------------- phase B: two parity chains, fp16 single-plane ring (r6 VERBATIM) ----------------
// o_t = v_t + Wh2 * o_{t-2}. 128 WGs x 512 thr: chain=bid&1, rank=bid>>1.
// Proven local optimum (497us scan): flag protocol, write-once slot per step,
// plain wide loads, per-WG flag after vmcnt-draining barrier. All perturbations
// (sentinel r2, consolidation r8, wave-flags r10, batch-split r11) regressed.
__global__ __launch_bounds__(512) void rnn_scan_kernel(
    const _Float16* __restrict__ w2,
    short* __restrict__ ring,                // [512][32768] shorts (fp16 bits)
    float* __restrict__ out,
    unsigned* __restrict__ flags)            // [2][64][32] uint, 128B stride
{
    __shared__ float ps[8 * 2 * 16 * 17];

    const int j = threadIdx.x;
    const int w = j >> 6, lane = j & 63;
    const int quad = lane >> 4, l15 = lane & 15;
    const int chain = blockIdx.x & 1;
    const int rank = blockIdx.x >> 1;
    const int n0 = rank * 32;

    unsigned* myflag = flags + (chain * 64 + rank) * 32;
    const unsigned* pollbase = flags + chain * 64 * 32;

    halfx8 af[2][8];
#pragma unroll
    for (int gt = 0; gt < 2; ++gt)
#pragma unroll
        for (int c = 0; c < 8; ++c) {
            int row = n0 + gt * 16 + l15;
            int k = w * 256 + c * 32 + quad * 8;
            af[gt][c] = *(const halfx8*)(w2 + (size_t)row * HDIM + k);
        }

    const int rn = j & 31, rb = j >> 5;
    const int gt_r = rn >> 4, row_r = rn & 15;

    for (int s = 0; s < 256; ++s) {
        const int t = chain + 2 * s;
        short* slot_next = ring + (size_t)(s * 2 + chain) * 32768;

        // prefetch v (overlaps poll latency)
        float uv = out[(size_t)rb * TH + (size_t)t * HDIM + n0 + rn];

        floatx4 acc[2][2] = {};
        if (s > 0) {
            const short* slot_prev = ring + (size_t)((s - 1) * 2 + chain) * 32768;
            // wave-local wait on this chain's 8 producers for wave w's K-slice
            if (lane < 8) {
                const unsigned* fp = pollbase + (w * 8 + lane) * 32;
                while (__hip_atomic_load(fp, __ATOMIC_RELAXED, __HIP_MEMORY_SCOPE_AGENT) < (unsigned)s) {}
            }
            __asm__ __volatile__("" ::: "memory");

#pragma unroll
            for (int c = 0; c < 8; ++c) {
                int kg = w * 32 + c * 4 + quad;
                halfx8 bh = *(const halfx8*)(slot_prev + kg * 128 + l15 * 8);
                int cp = c & 1;
                acc[0][cp] = __builtin_amdgcn_mfma_f32_16x16x32_f16(af[0][c], bh, acc[0][cp], 0, 0, 0);
                acc[1][cp] = __builtin_amdgcn_mfma_f32_16x16x32_f16(af[1][c], bh, acc[1][cp], 0, 0, 0);
            }
        }

        floatx4 a0 = acc[0][0] + acc[0][1];
        floatx4 a1 = acc[1][0] + acc[1][1];
#pragma unroll
        for (int r = 0; r < 4; ++r) {
            ps[((w * 2 + 0) * 16 + quad * 4 + r) * 17 + l15] = a0[r];
            ps[((w * 2 + 1) * 16 + quad * 4 + r) * 17 + l15] = a1[r];
        }
        __syncthreads();

        float sv_f = uv;
#pragma unroll
        for (int ww = 0; ww < 8; ++ww)
            sv_f += ps[((ww * 2 + gt_r) * 16 + row_r) * 17 + rb];

        int n = n0 + rn;

        // fp16 producer-side cast, pack (n, n+1) into one 4B relaxed agent store
        unsigned hb = f16bits(sv_f);
        unsigned hb2 = __shfl_down(hb, 1);
        if ((j & 1) == 0) {
            int idx = (n >> 3) * 128 + rb * 8 + (n & 7);  // n even -> 4B aligned
            __hip_atomic_store((unsigned*)(slot_next + idx), hb | (hb2 << 16),
                               __ATOMIC_RELAXED, __HIP_MEMORY_SCOPE_AGENT);
        }

        // barrier drains ring stores (vmcnt(0) before s_barrier), then publish
        __syncthreads();
        if (j == 0)
            __hip_atomic_store(myflag, (unsigned)(s + 1), __ATOMIC_RELAXED, __HIP_MEMORY_SCOPE_AGENT);

        // out stores AFTER the flag: off the inter-WG critical path
        out[(size_t)rb * TH + (size_t)t * HDIM + n] = sv_f;
        if (t == TLEN - 1) out[(size_t)OUT_MAIN + (size_t)rb * HDIM + n] = sv_f;
    }
}

// ---------------- launcher ----------------
extern "C" void kernel_launch(void* const* d_in, const int* in_sizes, int n_in,
                              void* d_out, int out_size, void* d_ws, size_t ws_size,
                              hipStream_t stream) {
    (void)in_sizes; (void)n_in; (void)out_size; (void)ws_size;
    const float* x    = (const float*)d_in[0];
    const float* W    = (const float*)d_in[1];
    const float* bias = (const float*)d_in[2];
    float* out = (float*)d_out;
    char* ws = (char*)d_ws;

    // Memory plan (80.0 MB + 16KB flags; fp16 single-plane everywhere):
    //  xh   [0,32M)   fp16 x          (dead after gemm_u)
    //  whT  [0,8M)    fp16 Wh^T       (transpose after gemm_u; dead after gemm_w2)
    //  w2   [8,16M)   fp16 Wh^2       (gemm_w2 -> scan)
    //  ring [16,48M)  512 slots x 64KB (scan only; aliases dead xh tail/wxh/whh)
    //  wxh  [32,40M)  fp16 Wx         (dead after gemm_u)
    //  whh  [40,48M)  fp16 Wh         (dead after gemm_w2)
    //  uh   [48,80M)  fp16 u          (dead after gemm_v)
    //  flags [80M,+16K)
    _Float16* xh  = (_Float16*)(ws);
    _Float16* whT = (_Float16*)(ws);
    _Float16* w2  = (_Float16*)(ws + 8388608);
    short*    ring = (short*)(ws + 16777216);
    _Float16* wxh = (_Float16*)(ws + 33554432);
    _Float16* whh = (_Float16*)(ws + 41943040);
    _Float16* uh  = (_Float16*)(ws + 50331648);
    unsigned* flags = (unsigned*)(ws + 83886080);

    hipMemsetAsync(ws + 83886080, 0, 16384, stream);

    cast_x_kernel<<<8192, 256, 0, stream>>>(x, xh, OUT_MAIN);
    cast_w_kernel<<<8192, 256, 0, stream>>>(W, wxh, whh);
    gemm_u_kernel<<<dim3(64, 16), 256, 0, stream>>>(xh, wxh, bias, out, uh);
    transpose_wh_kernel<<<dim3(64, 64), dim3(32, 8), 0, stream>>>(W, whT);
    gemm_v_kernel<<<dim3(64, 16), 256, 0, stream>>>(uh, whh, out);
    gemm_w2_kernel<<<dim3(16, 16), 256, 0, stream>>>(whh, whT, w2);
    rnn_scan_kernel<<<128, 512, 0, stream>>>(w2, ring, out, flags);
}

// Round 14
// 973.399 us; speedup vs baseline: 1.3459x; 1.0339x over previous
//
#include <hip/hip_runtime.h>
#include <hip/hip_fp16.h>
#include <stdint.h>

#define HDIM 2048
#define BATCH 16
#define TLEN 512
#define TH   1048576        // TLEN*HDIM
#define OUT_MAIN 16777216   // BATCH*TLEN*HDIM

using floatx4 = __attribute__((ext_vector_type(4))) float;
using shortx8 = __attribute__((ext_vector_type(8))) short;
using halfx8  = __attribute__((ext_vector_type(8))) _Float16;
typedef unsigned long long ull;

static __device__ __forceinline__ unsigned f16bits(float f) {
    _Float16 h = (_Float16)f;
    return (unsigned)*(unsigned short*)&h;
}

// Direct global->LDS 16B copy (m97 pattern): LDS dest is wave-uniform base,
// HW adds lane*16; global source is per-lane. No VGPR round-trip, no ds_write.
static __device__ __forceinline__ void glds16(const _Float16* g, short* l) {
    __builtin_amdgcn_global_load_lds(
        (const __attribute__((address_space(1))) void*)g,
        (__attribute__((address_space(3))) void*)l,
        16, 0, 0);
}

// ---------------- cast kernels ----------------
__global__ void cast_x_kernel(const float* __restrict__ x, _Float16* __restrict__ xh, int n) {
    int i = blockIdx.x * blockDim.x + threadIdx.x;
    int stride = gridDim.x * blockDim.x;
    for (; i < n; i += stride) xh[i] = (_Float16)x[i];
}

__global__ void cast_w_kernel(const float* __restrict__ W,
                              _Float16* __restrict__ wxh,
                              _Float16* __restrict__ whh) {
    int i = blockIdx.x * blockDim.x + threadIdx.x;
    int stride = gridDim.x * blockDim.x;
    for (; i < HDIM * HDIM; i += stride) {
        int g = i >> 11, k = i & (HDIM - 1);
        wxh[i] = (_Float16)W[g * (2 * HDIM) + k];
        whh[i] = (_Float16)W[g * (2 * HDIM) + HDIM + k];
    }
}

// Transpose Wh -> whT (fp16). Runs after gemm_u; output aliases dead xh.
__global__ void transpose_wh_kernel(const float* __restrict__ W,
                                    _Float16* __restrict__ whT) {
    __shared__ float tile[32][33];
    int bx = blockIdx.x * 32, by = blockIdx.y * 32;
    int tx = threadIdx.x, ty = threadIdx.y;  // (32,8)
#pragma unroll
    for (int r = 0; r < 32; r += 8)
        tile[ty + r][tx] = W[(size_t)(by + ty + r) * (2 * HDIM) + HDIM + bx + tx];
    __syncthreads();
#pragma unroll
    for (int r = 0; r < 32; r += 8)
        whT[(size_t)(bx + ty + r) * HDIM + by + tx] = (_Float16)tile[tx][ty + r];
}

// ---------------- phase A: u = x @ Wx^T + b -> out (fp32) + uh (fp16) ----------------
// Staging via global_load_lds (m97 single-buffer, 2 barriers/kt). Slot index
// for thread j is exactly j, so wave w's 64 lanes fill bytes [w*1024, w*1024+1024)
// -- wave-uniform base + lane*16, the required glds layout. Bit-identical math
// to the reg-staged version.
__global__ __launch_bounds__(256) void gemm_u_kernel(
    const _Float16* __restrict__ xh,
    const _Float16* __restrict__ wxh,
    const float* __restrict__ bias,
    float* __restrict__ out,
    _Float16* __restrict__ uh)
{
    __shared__ __align__(16) short As[4 * 128 * 8];
    __shared__ __align__(16) short Bs[4 * 128 * 8];

    const int j = threadIdx.x;
    const int m0 = blockIdx.x * 128;
    const int n0 = blockIdx.y * 128;
    const int w = j >> 6, lane = j & 63;
    const int wm = (w >> 1) * 64, wn = (w & 1) * 64;
    const int quad = lane >> 4, l15 = lane & 15;

    const int mA0 = j & 127, kg0 = j >> 7;
    const int wbase = w * 512;               // short offset of wave's LDS run

    const _Float16* gA0 = xh  + (size_t)(m0 + mA0) * HDIM + kg0 * 8;
    const _Float16* gA1 = gA0 + 16;          // kg0+2 chunk (slot j+256)
    const _Float16* gB0 = wxh + (size_t)(n0 + mA0) * HDIM + kg0 * 8;
    const _Float16* gB1 = gB0 + 16;

    floatx4 acc[4][4] = {};

    for (int kt = 0; kt < 64; ++kt) {
        int k = kt * 32;
        glds16(gA0 + k, As + wbase);
        glds16(gA1 + k, As + wbase + 2048);
        glds16(gB0 + k, Bs + wbase);
        glds16(gB1 + k, Bs + wbase + 2048);
        __syncthreads();   // vmcnt(0) drain -> LDS tile ready

        halfx8 af[4], bf[4];
#pragma unroll
        for (int mt = 0; mt < 4; ++mt)
            af[mt] = ((const halfx8*)As)[quad * 128 + wm + mt * 16 + l15];
#pragma unroll
        for (int nt = 0; nt < 4; ++nt)
            bf[nt] = ((const halfx8*)Bs)[quad * 128 + wn + nt * 16 + l15];
#pragma unroll
        for (int mt = 0; mt < 4; ++mt)
#pragma unroll
            for (int nt = 0; nt < 4; ++nt)
                acc[mt][nt] = __builtin_amdgcn_mfma_f32_16x16x32_f16(af[mt], bf[nt], acc[mt][nt], 0, 0, 0);
        __syncthreads();   // protect LDS before next overwrite
    }

#pragma unroll
    for (int nt = 0; nt < 4; ++nt) {
        int gn = n0 + wn + nt * 16 + l15;
        float bv = bias[gn];
#pragma unroll
        for (int mt = 0; mt < 4; ++mt) {
#pragma unroll
            for (int r = 0; r < 4; ++r) {
                int gm = m0 + wm + mt * 16 + quad * 4 + r;
                float v = acc[mt][nt][r] + bv;
                out[(size_t)gm * HDIM + gn] = v;
                uh[(size_t)gm * HDIM + gn] = (_Float16)v;
            }
        }
    }
}

// ---------------- Wh2 = Wh*Wh (fp16 single-plane, glds staging) ----------------
__global__ __launch_bounds__(256) void gemm_w2_kernel(
    const _Float16* __restrict__ whh,
    const _Float16* __restrict__ wT,
    _Float16* __restrict__ w2)
{
    __shared__ __align__(16) short As[4 * 128 * 8];
    __shared__ __align__(16) short Bs[4 * 128 * 8];

    const int j = threadIdx.x;
    const int m0 = blockIdx.x * 128;
    const int n0 = blockIdx.y * 128;
    const int w = j >> 6, lane = j & 63;
    const int wm = (w >> 1) * 64, wn = (w & 1) * 64;
    const int quad = lane >> 4, l15 = lane & 15;

    const int mA0 = j & 127, kg0 = j >> 7;
    const int wbase = w * 512;

    const _Float16* gA0 = whh + (size_t)(m0 + mA0) * HDIM + kg0 * 8;
    const _Float16* gA1 = gA0 + 16;
    const _Float16* gB0 = wT  + (size_t)(n0 + mA0) * HDIM + kg0 * 8;
    const _Float16* gB1 = gB0 + 16;

    floatx4 acc[4][4] = {};

    for (int kt = 0; kt < 64; ++kt) {
        int k = kt * 32;
        glds16(gA0 + k, As + wbase);
        glds16(gA1 + k, As + wbase + 2048);
        glds16(gB0 + k, Bs + wbase);
        glds16(gB1 + k, Bs + wbase + 2048);
        __syncthreads();

        halfx8 af[4], bf[4];
#pragma unroll
        for (int mt = 0; mt < 4; ++mt)
            af[mt] = ((const halfx8*)As)[quad * 128 + wm + mt * 16 + l15];
#pragma unroll
        for (int nt = 0; nt < 4; ++nt)
            bf[nt] = ((const halfx8*)Bs)[quad * 128 + wn + nt * 16 + l15];
#pragma unroll
        for (int mt = 0; mt < 4; ++mt)
#pragma unroll
            for (int nt = 0; nt < 4; ++nt)
                acc[mt][nt] = __builtin_amdgcn_mfma_f32_16x16x32_f16(af[mt], bf[nt], acc[mt][nt], 0, 0, 0);
        __syncthreads();
    }

#pragma unroll
    for (int nt = 0; nt < 4; ++nt) {
        int gn = n0 + wn + nt * 16 + l15;
#pragma unroll
        for (int mt = 0; mt < 4; ++mt)
#pragma unroll
            for (int r = 0; r < 4; ++r) {
                int gm = m0 + wm + mt * 16 + quad * 4 + r;
                w2[(size_t)gm * HDIM + gn] = (_Float16)acc[mt][nt][r];
            }
    }
}

// ---------------- v = u + Wh*u_shift (fp16; t==0 rows keep u; glds staging) ----------------
__global__ __launch_bounds__(256) void gemm_v_kernel(
    const _Float16* __restrict__ uh,
    const _Float16* __restrict__ whh,
    float* __restrict__ out)
{
    __shared__ __align__(16) short As[4 * 128 * 8];
    __shared__ __align__(16) short Bs[4 * 128 * 8];

    const int j = threadIdx.x;
    const int m0 = blockIdx.x * 128;
    const int n0 = blockIdx.y * 128;
    const int w = j >> 6, lane = j & 63;
    const int wm = (w >> 1) * 64, wn = (w & 1) * 64;
    const int quad = lane >> 4, l15 = lane & 15;

    const int mA0 = j & 127, kg0 = j >> 7;
    const int wbase = w * 512;

    int rowA = m0 + mA0 - 1; if (rowA < 0) rowA = 0;

    const _Float16* gA0 = uh  + (size_t)rowA * HDIM + kg0 * 8;
    const _Float16* gA1 = gA0 + 16;
    const _Float16* gB0 = whh + (size_t)(n0 + mA0) * HDIM + kg0 * 8;
    const _Float16* gB1 = gB0 + 16;

    floatx4 acc[4][4] = {};

    for (int kt = 0; kt < 64; ++kt) {
        int k = kt * 32;
        glds16(gA0 + k, As + wbase);
        glds16(gA1 + k, As + wbase + 2048);
        glds16(gB0 + k, Bs + wbase);
        glds16(gB1 + k, Bs + wbase + 2048);
        __syncthreads();

        halfx8 af[4], bf[4];
#pragma unroll
        for (int mt = 0; mt < 4; ++mt)
            af[mt] = ((const halfx8*)As)[quad * 128 + wm + mt * 16 + l15];
#pragma unroll
        for (int nt = 0; nt < 4; ++nt)
            bf[nt] = ((const halfx8*)Bs)[quad * 128 + wn + nt * 16 + l15];
#pragma unroll
        for (int mt = 0; mt < 4; ++mt)
#pragma unroll
            for (int nt = 0; nt < 4; ++nt)
                acc[mt][nt] = __builtin_amdgcn_mfma_f32_16x16x32_f16(af[mt], bf[nt], acc[mt][nt], 0, 0, 0);
        __syncthreads();
    }

#pragma unroll
    for (int nt = 0; nt < 4; ++nt) {
        int gn = n0 + wn + nt * 16 + l15;
#pragma unroll
        for (int mt = 0; mt < 4; ++mt)
#pragma unroll
            for (int r = 0; r < 4; ++r) {
                int gm = m0 + wm + mt * 16 + quad * 4 + r;
                float uval = out[(size_t)gm * HDIM + gn];
                float res = ((gm & 511) == 0) ? uval : (acc[mt][nt][r] + uval);
                out[(size_t)gm * HDIM + gn] = res;
            }
    }
}

// ---------------- phase B: two parity chains, fp16 single-plane ring (r6 VERBATIM) ----------------
// o_t = v_t + Wh2 * o_{t-2}. 128 WGs x 512 thr: chain=bid&1, rank=bid>>1.
// Proven local optimum (497us scan): flag protocol, write-once slot per step,
// plain wide loads, per-WG flag after vmcnt-draining barrier. All perturbations
// (sentinel r2, consolidation r8, wave-flags r10, batch-split r11) regressed.
__global__ __launch_bounds__(512) void rnn_scan_kernel(
    const _Float16* __restrict__ w2,
    short* __restrict__ ring,                // [512][32768] shorts (fp16 bits)
    float* __restrict__ out,
    unsigned* __restrict__ flags)            // [2][64][32] uint, 128B stride
{
    __shared__ float ps[8 * 2 * 16 * 17];

    const int j = threadIdx.x;
    const int w = j >> 6, lane = j & 63;
    const int quad = lane >> 4, l15 = lane & 15;
    const int chain = blockIdx.x & 1;
    const int rank = blockIdx.x >> 1;
    const int n0 = rank * 32;

    unsigned* myflag = flags + (chain * 64 + rank) * 32;
    const unsigned* pollbase = flags + chain * 64 * 32;

    halfx8 af[2][8];
#pragma unroll
    for (int gt = 0; gt < 2; ++gt)
#pragma unroll
        for (int c = 0; c < 8; ++c) {
            int row = n0 + gt * 16 + l15;
            int k = w * 256 + c * 32 + quad * 8;
            af[gt][c] = *(const halfx8*)(w2 + (size_t)row * HDIM + k);
        }

    const int rn = j & 31, rb = j >> 5;
    const int gt_r = rn >> 4, row_r = rn & 15;

    for (int s = 0; s < 256; ++s) {
        const int t = chain + 2 * s;
        short* slot_next = ring + (size_t)(s * 2 + chain) * 32768;

        // prefetch v (overlaps poll latency)
        float uv = out[(size_t)rb * TH + (size_t)t * HDIM + n0 + rn];

        floatx4 acc[2][2] = {};
        if (s > 0) {
            const short* slot_prev = ring + (size_t)((s - 1) * 2 + chain) * 32768;
            // wave-local wait on this chain's 8 producers for wave w's K-slice
            if (lane < 8) {
                const unsigned* fp = pollbase + (w * 8 + lane) * 32;
                while (__hip_atomic_load(fp, __ATOMIC_RELAXED, __HIP_MEMORY_SCOPE_AGENT) < (unsigned)s) {}
            }
            __asm__ __volatile__("" ::: "memory");

#pragma unroll
            for (int c = 0; c < 8; ++c) {
                int kg = w * 32 + c * 4 + quad;
                halfx8 bh = *(const halfx8*)(slot_prev + kg * 128 + l15 * 8);
                int cp = c & 1;
                acc[0][cp] = __builtin_amdgcn_mfma_f32_16x16x32_f16(af[0][c], bh, acc[0][cp], 0, 0, 0);
                acc[1][cp] = __builtin_amdgcn_mfma_f32_16x16x32_f16(af[1][c], bh, acc[1][cp], 0, 0, 0);
            }
        }

        floatx4 a0 = acc[0][0] + acc[0][1];
        floatx4 a1 = acc[1][0] + acc[1][1];
#pragma unroll
        for (int r = 0; r < 4; ++r) {
            ps[((w * 2 + 0) * 16 + quad * 4 + r) * 17 + l15] = a0[r];
            ps[((w * 2 + 1) * 16 + quad * 4 + r) * 17 + l15] = a1[r];
        }
        __syncthreads();

        float sv_f = uv;
#pragma unroll
        for (int ww = 0; ww < 8; ++ww)
            sv_f += ps[((ww * 2 + gt_r) * 16 + row_r) * 17 + rb];

        int n = n0 + rn;

        // fp16 producer-side cast, pack (n, n+1) into one 4B relaxed agent store
        unsigned hb = f16bits(sv_f);
        unsigned hb2 = __shfl_down(hb, 1);
        if ((j & 1) == 0) {
            int idx = (n >> 3) * 128 + rb * 8 + (n & 7);  // n even -> 4B aligned
            __hip_atomic_store((unsigned*)(slot_next + idx), hb | (hb2 << 16),
                               __ATOMIC_RELAXED, __HIP_MEMORY_SCOPE_AGENT);
        }

        // barrier drains ring stores (vmcnt(0) before s_barrier), then publish
        __syncthreads();
        if (j == 0)
            __hip_atomic_store(myflag, (unsigned)(s + 1), __ATOMIC_RELAXED, __HIP_MEMORY_SCOPE_AGENT);

        // out stores AFTER the flag: off the inter-WG critical path
        out[(size_t)rb * TH + (size_t)t * HDIM + n] = sv_f;
        if (t == TLEN - 1) out[(size_t)OUT_MAIN + (size_t)rb * HDIM + n] = sv_f;
    }
}

// ---------------- launcher ----------------
extern "C" void kernel_launch(void* const* d_in, const int* in_sizes, int n_in,
                              void* d_out, int out_size, void* d_ws, size_t ws_size,
                              hipStream_t stream) {
    (void)in_sizes; (void)n_in; (void)out_size; (void)ws_size;
    const float* x    = (const float*)d_in[0];
    const float* W    = (const float*)d_in[1];
    const float* bias = (const float*)d_in[2];
    float* out = (float*)d_out;
    char* ws = (char*)d_ws;

    // Memory plan (80.0 MB + 16KB flags; fp16 single-plane everywhere):
    //  xh   [0,32M)   fp16 x          (dead after gemm_u)
    //  whT  [0,8M)    fp16 Wh^T       (transpose after gemm_u; dead after gemm_w2)
    //  w2   [8,16M)   fp16 Wh^2       (gemm_w2 -> scan)
    //  ring [16,48M)  512 slots x 64KB (scan only; aliases dead xh tail/wxh/whh)
    //  wxh  [32,40M)  fp16 Wx         (dead after gemm_u)
    //  whh  [40,48M)  fp16 Wh         (dead after gemm_w2)
    //  uh   [48,80M)  fp16 u          (dead after gemm_v)
    //  flags [80M,+16K)
    _Float16* xh  = (_Float16*)(ws);
    _Float16* whT = (_Float16*)(ws);
    _Float16* w2  = (_Float16*)(ws + 8388608);
    short*    ring = (short*)(ws + 16777216);
    _Float16* wxh = (_Float16*)(ws + 33554432);
    _Float16* whh = (_Float16*)(ws + 41943040);
    _Float16* uh  = (_Float16*)(ws + 50331648);
    unsigned* flags = (unsigned*)(ws + 83886080);

    hipMemsetAsync(ws + 83886080, 0, 16384, stream);

    cast_x_kernel<<<8192, 256, 0, stream>>>(x, xh, OUT_MAIN);
    cast_w_kernel<<<8192, 256, 0, stream>>>(W, wxh, whh);
    gemm_u_kernel<<<dim3(64, 16), 256, 0, stream>>>(xh, wxh, bias, out, uh);
    transpose_wh_kernel<<<dim3(64, 64), dim3(32, 8), 0, stream>>>(W, whT);
    gemm_v_kernel<<<dim3(64, 16), 256, 0, stream>>>(uh, whh, out);
    gemm_w2_kernel<<<dim3(16, 16), 256, 0, stream>>>(whh, whT, w2);
    rnn_scan_kernel<<<128, 512, 0, stream>>>(w2, ring, out, flags);
}

// Round 17
// 968.460 us; speedup vs baseline: 1.3528x; 1.0051x over previous
//
#include <hip/hip_runtime.h>
#include <hip/hip_fp16.h>
#include <stdint.h>

#define HDIM 2048
#define BATCH 16
#define TLEN 512
#define TH   1048576        // TLEN*HDIM
#define OUT_MAIN 16777216   // BATCH*TLEN*HDIM

using floatx4 = __attribute__((ext_vector_type(4))) float;
using shortx4 = __attribute__((ext_vector_type(4))) short;
using shortx8 = __attribute__((ext_vector_type(8))) short;
using halfx8  = __attribute__((ext_vector_type(8))) _Float16;
typedef unsigned long long ull;

static __device__ __forceinline__ unsigned f16bits(float f) {
    _Float16 h = (_Float16)f;
    return (unsigned)*(unsigned short*)&h;
}

// Direct global->LDS 16B copy (m97 pattern): LDS dest is wave-uniform base,
// HW adds lane*16; global source is per-lane. No VGPR round-trip, no ds_write.
static __device__ __forceinline__ void glds16(const _Float16* g, short* l) {
    __builtin_amdgcn_global_load_lds(
        (const __attribute__((address_space(1))) void*)g,
        (__attribute__((address_space(3))) void*)l,
        16, 0, 0);
}

// ---------------- cast x (vectorized: float4 in, 4xfp16 8B out) ----------------
__global__ void cast_x_kernel(const float* __restrict__ x, _Float16* __restrict__ xh, int n4) {
    int i = blockIdx.x * blockDim.x + threadIdx.x;
    int stride = gridDim.x * blockDim.x;
    for (; i < n4; i += stride) {
        floatx4 v = *(const floatx4*)(x + (size_t)i * 4);
        shortx4 o;
#pragma unroll
        for (int e = 0; e < 4; ++e) {
            _Float16 h = (_Float16)v[e];
            o[e] = *(short*)&h;
        }
        *(shortx4*)(xh + (size_t)i * 4) = o;
    }
}

// ---------------- W prep: one pass over W -> wxh, whh, whT (all fp16) ----------------
// Replaces cast_w + transpose_wh. Tile (bx,by) handles 32x32 of both halves.
__global__ void wprep_kernel(const float* __restrict__ W,
                             _Float16* __restrict__ wxh,
                             _Float16* __restrict__ whh,
                             _Float16* __restrict__ whT) {
    __shared__ float tile[32][33];
    int bx = blockIdx.x * 32, by = blockIdx.y * 32;
    int tx = threadIdx.x, ty = threadIdx.y;  // (32,8)
#pragma unroll
    for (int r = 0; r < 32; r += 8) {
        int row = by + ty + r, col = bx + tx;
        // Wx half: cast only
        wxh[(size_t)row * HDIM + col] = (_Float16)W[(size_t)row * (2 * HDIM) + col];
        // Wh half: cast + stage for transpose
        float v = W[(size_t)row * (2 * HDIM) + HDIM + col];
        tile[ty + r][tx] = v;
        whh[(size_t)row * HDIM + col] = (_Float16)v;
    }
    __syncthreads();
#pragma unroll
    for (int r = 0; r < 32; r += 8)
        whT[(size_t)(bx + ty + r) * HDIM + by + tx] = (_Float16)tile[tx][ty + r];
}

// ---------------- phase A: u = x @ Wx^T + b -> out (fp32) + uh (fp16) ----------------
// Staging via global_load_lds (m97 single-buffer, 2 barriers/kt). Bit-identical
// math to the reg-staged version. (r14 verbatim)
__global__ __launch_bounds__(256) void gemm_u_kernel(
    const _Float16* __restrict__ xh,
    const _Float16* __restrict__ wxh,
    const float* __restrict__ bias,
    float* __restrict__ out,
    _Float16* __restrict__ uh)
{
    __shared__ __align__(16) short As[4 * 128 * 8];
    __shared__ __align__(16) short Bs[4 * 128 * 8];

    const int j = threadIdx.x;
    const int m0 = blockIdx.x * 128;
    const int n0 = blockIdx.y * 128;
    const int w = j >> 6, lane = j & 63;
    const int wm = (w >> 1) * 64, wn = (w & 1) * 64;
    const int quad = lane >> 4, l15 = lane & 15;

    const int mA0 = j & 127, kg0 = j >> 7;
    const int wbase = w * 512;               // short offset of wave's LDS run

    const _Float16* gA0 = xh  + (size_t)(m0 + mA0) * HDIM + kg0 * 8;
    const _Float16* gA1 = gA0 + 16;          // kg0+2 chunk (slot j+256)
    const _Float16* gB0 = wxh + (size_t)(n0 + mA0) * HDIM + kg0 * 8;
    const _Float16* gB1 = gB0 + 16;

    floatx4 acc[4][4] = {};

    for (int kt = 0; kt < 64; ++kt) {
        int k = kt * 32;
        glds16(gA0 + k, As + wbase);
        glds16(gA1 + k, As + wbase + 2048);
        glds16(gB0 + k, Bs + wbase);
        glds16(gB1 + k, Bs + wbase + 2048);
        __syncthreads();   // vmcnt(0) drain -> LDS tile ready

        halfx8 af[4], bf[4];
#pragma unroll
        for (int mt = 0; mt < 4; ++mt)
            af[mt] = ((const halfx8*)As)[quad * 128 + wm + mt * 16 + l15];
#pragma unroll
        for (int nt = 0; nt < 4; ++nt)
            bf[nt] = ((const halfx8*)Bs)[quad * 128 + wn + nt * 16 + l15];
#pragma unroll
        for (int mt = 0; mt < 4; ++mt)
#pragma unroll
            for (int nt = 0; nt < 4; ++nt)
                acc[mt][nt] = __builtin_amdgcn_mfma_f32_16x16x32_f16(af[mt], bf[nt], acc[mt][nt], 0, 0, 0);
        __syncthreads();   // protect LDS before next overwrite
    }

#pragma unroll
    for (int nt = 0; nt < 4; ++nt) {
        int gn = n0 + wn + nt * 16 + l15;
        float bv = bias[gn];
#pragma unroll
        for (int mt = 0; mt < 4; ++mt) {
#pragma unroll
            for (int r = 0; r < 4; ++r) {
                int gm = m0 + wm + mt * 16 + quad * 4 + r;
                float v = acc[mt][nt][r] + bv;
                out[(size_t)gm * HDIM + gn] = v;
                uh[(size_t)gm * HDIM + gn] = (_Float16)v;
            }
        }
    }
}

// ---------------- Wh2 = Wh*Wh (fp16 single-plane, glds staging; r14 verbatim) ----------------
__global__ __launch_bounds__(256) void gemm_w2_kernel(
    const _Float16* __restrict__ whh,
    const _Float16* __restrict__ wT,
    _Float16* __restrict__ w2)
{
    __shared__ __align__(16) short As[4 * 128 * 8];
    __shared__ __align__(16) short Bs[4 * 128 * 8];

    const int j = threadIdx.x;
    const int m0 = blockIdx.x * 128;
    const int n0 = blockIdx.y * 128;
    const int w = j >> 6, lane = j & 63;
    const int wm = (w >> 1) * 64, wn = (w & 1) * 64;
    const int quad = lane >> 4, l15 = lane & 15;

    const int mA0 = j & 127, kg0 = j >> 7;
    const int wbase = w * 512;

    const _Float16* gA0 = whh + (size_t)(m0 + mA0) * HDIM + kg0 * 8;
    const _Float16* gA1 = gA0 + 16;
    const _Float16* gB0 = wT  + (size_t)(n0 + mA0) * HDIM + kg0 * 8;
    const _Float16* gB1 = gB0 + 16;

    floatx4 acc[4][4] = {};

    for (int kt = 0; kt < 64; ++kt) {
        int k = kt * 32;
        glds16(gA0 + k, As + wbase);
        glds16(gA1 + k, As + wbase + 2048);
        glds16(gB0 + k, Bs + wbase);
        glds16(gB1 + k, Bs + wbase + 2048);
        __syncthreads();

        halfx8 af[4], bf[4];
#pragma unroll
        for (int mt = 0; mt < 4; ++mt)
            af[mt] = ((const halfx8*)As)[quad * 128 + wm + mt * 16 + l15];
#pragma unroll
        for (int nt = 0; nt < 4; ++nt)
            bf[nt] = ((const halfx8*)Bs)[quad * 128 + wn + nt * 16 + l15];
#pragma unroll
        for (int mt = 0; mt < 4; ++mt)
#pragma unroll
            for (int nt = 0; nt < 4; ++nt)
                acc[mt][nt] = __builtin_amdgcn_mfma_f32_16x16x32_f16(af[mt], bf[nt], acc[mt][nt], 0, 0, 0);
        __syncthreads();
    }

#pragma unroll
    for (int nt = 0; nt < 4; ++nt) {
        int gn = n0 + wn + nt * 16 + l15;
#pragma unroll
        for (int mt = 0; mt < 4; ++mt)
#pragma unroll
            for (int r = 0; r < 4; ++r) {
                int gm = m0 + wm + mt * 16 + quad * 4 + r;
                w2[(size_t)gm * HDIM + gn] = (_Float16)acc[mt][nt][r];
            }
    }
}

// ---------------- v = u + Wh*u_shift (fp16; t==0 rows keep u; glds; r14 verbatim) ----------------
__global__ __launch_bounds__(256) void gemm_v_kernel(
    const _Float16* __restrict__ uh,
    const _Float16* __restrict__ whh,
    float* __restrict__ out)
{
    __shared__ __align__(16) short As[4 * 128 * 8];
    __shared__ __align__(16) short Bs[4 * 128 * 8];

    const int j = threadIdx.x;
    const int m0 = blockIdx.x * 128;
    const int n0 = blockIdx.y * 128;
    const int w = j >> 6, lane = j & 63;
    const int wm = (w >> 1) * 64, wn = (w & 1) * 64;
    const int quad = lane >> 4, l15 = lane & 15;

    const int mA0 = j & 127, kg0 = j >> 7;
    const int wbase = w * 512;

    int rowA = m0 + mA0 - 1; if (rowA < 0) rowA = 0;

    const _Float16* gA0 = uh  + (size_t)rowA * HDIM + kg0 * 8;
    const _Float16* gA1 = gA0 + 16;
    const _Float16* gB0 = whh + (size_t)(n0 + mA0) * HDIM + kg0 * 8;
    const _Float16* gB1 = gB0 + 16;

    floatx4 acc[4][4] = {};

    for (int kt = 0; kt < 64; ++kt) {
        int k = kt * 32;
        glds16(gA0 + k, As + wbase);
        glds16(gA1 + k, As + wbase + 2048);
        glds16(gB0 + k, Bs + wbase);
        glds16(gB1 + k, Bs + wbase + 2048);
        __syncthreads();

        halfx8 af[4], bf[4];
#pragma unroll
        for (int mt = 0; mt < 4; ++mt)
            af[mt] = ((const halfx8*)As)[quad * 128 + wm + mt * 16 + l15];
#pragma unroll
        for (int nt = 0; nt < 4; ++nt)
            bf[nt] = ((const halfx8*)Bs)[quad * 128 + wn + nt * 16 + l15];
#pragma unroll
        for (int mt = 0; mt < 4; ++mt)
#pragma unroll
            for (int nt = 0; nt < 4; ++nt)
                acc[mt][nt] = __builtin_amdgcn_mfma_f32_16x16x32_f16(af[mt], bf[nt], acc[mt][nt], 0, 0, 0);
        __syncthreads();
    }

#pragma unroll
    for (int nt = 0; nt < 4; ++nt) {
        int gn = n0 + wn + nt * 16 + l15;
#pragma unroll
        for (int mt = 0; mt < 4; ++mt)
#pragma unroll
            for (int r = 0; r < 4; ++r) {
                int gm = m0 + wm + mt * 16 + quad * 4 + r;
                float uval = out[(size_t)gm * HDIM + gn];
                float res = ((gm & 511) == 0) ? uval : (acc[mt][nt][r] + uval);
                out[(size_t)gm * HDIM + gn] = res;
            }
    }
}

// ---------------- phase B: two parity chains, fp16 single-plane ring (r6 VERBATIM) ----------------
// o_t = v_t + Wh2 * o_{t-2}. 128 WGs x 512 thr: chain=bid&1, rank=bid>>1.
// Proven local optimum (~480-497us scan): flag protocol, write-once slot per
// step, plain wide loads, per-WG flag after vmcnt-draining barrier. All
// perturbations (sentinel r2, consolidation r8, wave-flags r10, batch-split
// r11) regressed. DO NOT TOUCH.
__global__ __launch_bounds__(512) void rnn_scan_kernel(
    const _Float16* __restrict__ w2,
    short* __restrict__ ring,                // [512][32768] shorts (fp16 bits)
    float* __restrict__ out,
    unsigned* __restrict__ flags)            // [2][64][32] uint, 128B stride
{
    __shared__ float ps[8 * 2 * 16 * 17];

    const int j = threadIdx.x;
    const int w = j >> 6, lane = j & 63;
    const int quad = lane >> 4, l15 = lane & 15;
    const int chain = blockIdx.x & 1;
    const int rank = blockIdx.x >> 1;
    const int n0 = rank * 32;

    unsigned* myflag = flags + (chain * 64 + rank) * 32;
    const unsigned* pollbase = flags + chain * 64 * 32;

    halfx8 af[2][8];
#pragma unroll
    for (int gt = 0; gt < 2; ++gt)
#pragma unroll
        for (int c = 0; c < 8; ++c) {
            int row = n0 + gt * 16 + l15;
            int k = w * 256 + c * 32 + quad * 8;
            af[gt][c] = *(const halfx8*)(w2 + (size_t)row * HDIM + k);
        }

    const int rn = j & 31, rb = j >> 5;
    const int gt_r = rn >> 4, row_r = rn & 15;

    for (int s = 0; s < 256; ++s) {
        const int t = chain + 2 * s;
        short* slot_next = ring + (size_t)(s * 2 + chain) * 32768;

        // prefetch v (overlaps poll latency)
        float uv = out[(size_t)rb * TH + (size_t)t * HDIM + n0 + rn];

        floatx4 acc[2][2] = {};
        if (s > 0) {
            const short* slot_prev = ring + (size_t)((s - 1) * 2 + chain) * 32768;
            // wave-local wait on this chain's 8 producers for wave w's K-slice
            if (lane < 8) {
                const unsigned* fp = pollbase + (w * 8 + lane) * 32;
                while (__hip_atomic_load(fp, __ATOMIC_RELAXED, __HIP_MEMORY_SCOPE_AGENT) < (unsigned)s) {}
            }
            __asm__ __volatile__("" ::: "memory");

#pragma unroll
            for (int c = 0; c < 8; ++c) {
                int kg = w * 32 + c * 4 + quad;
                halfx8 bh = *(const halfx8*)(slot_prev + kg * 128 + l15 * 8);
                int cp = c & 1;
                acc[0][cp] = __builtin_amdgcn_mfma_f32_16x16x32_f16(af[0][c], bh, acc[0][cp], 0, 0, 0);
                acc[1][cp] = __builtin_amdgcn_mfma_f32_16x16x32_f16(af[1][c], bh, acc[1][cp], 0, 0, 0);
            }
        }

        floatx4 a0 = acc[0][0] + acc[0][1];
        floatx4 a1 = acc[1][0] + acc[1][1];
#pragma unroll
        for (int r = 0; r < 4; ++r) {
            ps[((w * 2 + 0) * 16 + quad * 4 + r) * 17 + l15] = a0[r];
            ps[((w * 2 + 1) * 16 + quad * 4 + r) * 17 + l15] = a1[r];
        }
        __syncthreads();

        float sv_f = uv;
#pragma unroll
        for (int ww = 0; ww < 8; ++ww)
            sv_f += ps[((ww * 2 + gt_r) * 16 + row_r) * 17 + rb];

        int n = n0 + rn;

        // fp16 producer-side cast, pack (n, n+1) into one 4B relaxed agent store
        unsigned hb = f16bits(sv_f);
        unsigned hb2 = __shfl_down(hb, 1);
        if ((j & 1) == 0) {
            int idx = (n >> 3) * 128 + rb * 8 + (n & 7);  // n even -> 4B aligned
            __hip_atomic_store((unsigned*)(slot_next + idx), hb | (hb2 << 16),
                               __ATOMIC_RELAXED, __HIP_MEMORY_SCOPE_AGENT);
        }

        // barrier drains ring stores (vmcnt(0) before s_barrier), then publish
        __syncthreads();
        if (j == 0)
            __hip_atomic_store(myflag, (unsigned)(s + 1), __ATOMIC_RELAXED, __HIP_MEMORY_SCOPE_AGENT);

        // out stores AFTER the flag: off the inter-WG critical path
        out[(size_t)rb * TH + (size_t)t * HDIM + n] = sv_f;
        if (t == TLEN - 1) out[(size_t)OUT_MAIN + (size_t)rb * HDIM + n] = sv_f;
    }
}

// ---------------- launcher ----------------
extern "C" void kernel_launch(void* const* d_in, const int* in_sizes, int n_in,
                              void* d_out, int out_size, void* d_ws, size_t ws_size,
                              hipStream_t stream) {
    (void)in_sizes; (void)n_in; (void)out_size; (void)ws_size;
    const float* x    = (const float*)d_in[0];
    const float* W    = (const float*)d_in[1];
    const float* bias = (const float*)d_in[2];
    float* out = (float*)d_out;
    char* ws = (char*)d_ws;

    // Memory plan (92.29 MB total; ws proven >= 92.4 MB):
    //  xh   [0,32M)       fp16 x       (dead after gemm_u)
    //  w2   [8,16M)       fp16 Wh^2    (written by gemm_w2 after gemm_v; xh dead)
    //  ring [16,48M)      scan only    (aliases dead xh tail/wxh/whh)
    //  wxh  [32,40M)      fp16 Wx      (dead after gemm_u)
    //  whh  [40,48M)      fp16 Wh      (dead after gemm_w2)
    //  uh   [48,80M)      fp16 u       (dead after gemm_v)
    //  flags[80M,+16K)
    //  whT  [80M+16K,+8M) fp16 Wh^T    (written by wprep BEFORE gemm_u; its own
    //                     region so wprep can run first; dead after gemm_w2)
    _Float16* xh  = (_Float16*)(ws);
    _Float16* w2  = (_Float16*)(ws + 8388608);
    short*    ring = (short*)(ws + 16777216);
    _Float16* wxh = (_Float16*)(ws + 33554432);
    _Float16* whh = (_Float16*)(ws + 41943040);
    _Float16* uh  = (_Float16*)(ws + 50331648);
    unsigned* flags = (unsigned*)(ws + 83886080);
    _Float16* whT = (_Float16*)(ws + 83886080 + 16384);

    hipMemsetAsync(ws + 83886080, 0, 16384, stream);

    cast_x_kernel<<<8192, 256, 0, stream>>>(x, xh, OUT_MAIN / 4);
    wprep_kernel<<<dim3(64, 64), dim3(32, 8), 0, stream>>>(W, wxh, whh, whT);
    gemm_u_kernel<<<dim3(64, 16), 256, 0, stream>>>(xh, wxh, bias, out, uh);
    gemm_v_kernel<<<dim3(64, 16), 256, 0, stream>>>(uh, whh, out);
    gemm_w2_kernel<<<dim3(16, 16), 256, 0, stream>>>(whh, whT, w2);
    rnn_scan_kernel<<<128, 512, 0, stream>>>(w2, ring, out, flags);
}